// Round 7
// baseline (286.009 us; speedup 1.0000x reference)
//
#include <hip/hip_runtime.h>
#include <hip/hip_bf16.h>

typedef unsigned int uint_t;
typedef unsigned short ushort_t;
typedef __attribute__((ext_vector_type(8))) short short8;
typedef __attribute__((ext_vector_type(4))) float floatx4;

__device__ __forceinline__ float4 fma4(float4 a, float s, float4 w){
  a.x += s*w.x; a.y += s*w.y; a.z += s*w.z; a.w += s*w.w; return a;
}
__device__ __forceinline__ float4 relu4(float4 a){
  return make_float4(fmaxf(a.x,0.f),fmaxf(a.y,0.f),fmaxf(a.z,0.f),fmaxf(a.w,0.f));
}
__device__ __forceinline__ float comp4(float4 v, int k){
  return k==0? v.x : k==1? v.y : k==2? v.z : v.w;
}
__device__ __forceinline__ unsigned bf16rne(float f){
  unsigned u = __float_as_uint(f);
  return (u + 0x7fffu + ((u>>16)&1u)) >> 16;
}
__device__ __forceinline__ uint_t packbf(float f){
  unsigned hb = bf16rne(f);
  float hf = __uint_as_float(hb<<16);
  unsigned lb = bf16rne(f - hf);
  return (hb<<16) | lb;
}
__device__ __forceinline__ uint4 pack4(float4 v){
  uint4 u; u.x=packbf(v.x); u.y=packbf(v.y); u.z=packbf(v.z); u.w=packbf(v.w); return u;
}

// =============== K1 fused: enc (blocks 0..127) + weight convert (blocks 128..1343) ===============
__global__ __launch_bounds__(256) void prep_kernel(
    const float* __restrict__ obs,
    const float* __restrict__ enc_w1, const float* __restrict__ enc_b1,
    const float* __restrict__ enc_w2, const float* __restrict__ enc_b2,
    const float* __restrict__ wl1, const float* __restrict__ wr1,
    const float* __restrict__ wl2, const float* __restrict__ wr2,
    const float* __restrict__ q_w1, const float* __restrict__ v_w1,
    ushort_t* __restrict__ wl1Thi, ushort_t* __restrict__ wl1Tlo,
    ushort_t* __restrict__ wr1Thi, ushort_t* __restrict__ wr1Tlo,
    ushort_t* __restrict__ wl2Thi, ushort_t* __restrict__ wl2Tlo,
    ushort_t* __restrict__ wr2Thi, ushort_t* __restrict__ wr2Tlo,
    ushort_t* __restrict__ qw1Thi, ushort_t* __restrict__ qw1Tlo,
    ushort_t* __restrict__ vw1Thi, ushort_t* __restrict__ vw1Tlo,
    uint_t* __restrict__ xpk,     // [4096][128] packed
    uint_t* __restrict__ xcatpk,  // [128][1152] packed
    unsigned* __restrict__ adjw, int* __restrict__ aiw)
{
  const int t = threadIdx.x, bid = blockIdx.x;
  if (bid >= 128){
    // ---------------- weight transpose + bf16 hi/lo convert ----------------
    __shared__ float sm[32][33];
    const int cw = bid - 128;
    const float* in; ushort_t* ohi; ushort_t* olo; int K, N, tt;
    if (cw < 64)        { in=wl1;  ohi=wl1Thi; olo=wl1Tlo; K=128;  N=512; tt=cw; }
    else if (cw < 128)  { in=wr1;  ohi=wr1Thi; olo=wr1Tlo; K=128;  N=512; tt=cw-64; }
    else if (cw < 384)  { in=wl2;  ohi=wl2Thi; olo=wl2Tlo; K=512;  N=512; tt=cw-128; }
    else if (cw < 640)  { in=wr2;  ohi=wr2Thi; olo=wr2Tlo; K=512;  N=512; tt=cw-384; }
    else if (cw < 928)  { in=q_w1; ohi=qw1Thi; olo=qw1Tlo; K=1152; N=256; tt=cw-640; }
    else                { in=v_w1; ohi=vw1Thi; olo=vw1Tlo; K=1152; N=256; tt=cw-928; }
    const int ktiles = K>>5;
    const int kt = tt % ktiles, nt = tt / ktiles;
    const int r = t>>5, c = t&31;
    #pragma unroll
    for (int i=0;i<4;i++)
      sm[r+i*8][c] = in[(size_t)(kt*32 + r + i*8)*N + nt*32 + c];
    __syncthreads();
    #pragma unroll
    for (int i=0;i<4;i++){
      const int n = nt*32 + r + i*8, k = kt*32 + c;
      const float f = sm[c][r+i*8];
      const unsigned hb = bf16rne(f);
      const float hf = __uint_as_float(hb<<16);
      const unsigned lb = bf16rne(f - hf);
      ohi[(size_t)n*K + k] = (ushort_t)hb;
      olo[(size_t)n*K + k] = (ushort_t)lb;
    }
    return;
  }
  // ---------------- encoder + adjacency + x1 tap ----------------
  __shared__ float s_pos[64];
  __shared__ float s_feats[512];
  __shared__ __align__(16) float s_h[32*132];
  __shared__ int s_ai;
  const int s = bid;
  const float* ob = obs + s*577;

  if (t < 64) s_pos[t] = ob[(t>>1)*18 + (t&1)];
  for (int e=t; e<512; e+=256){ const int i=e>>4, f=e&15; s_feats[e] = ob[i*18+2+f]; }
  if (t==0){
    float a = ob[576];
    a = fminf(fmaxf(a, 0.f), 31.f);
    const int ai = (int)a;
    s_ai = ai; aiw[s] = ai;
  }
  __syncthreads();

  if (t < 32){
    const float px = s_pos[2*t], py = s_pos[2*t+1];
    const float R2 = 0.09f;
    unsigned m = 0u;
    for (int j=0;j<32;j++){
      const float dx = __fsub_rn(px, s_pos[2*j]), dy = __fsub_rn(py, s_pos[2*j+1]);
      const float d2 = __fadd_rn(__fmul_rn(dx,dx), __fmul_rn(dy,dy));
      if (d2 <= R2 || j==t) m |= (1u<<j);
    }
    adjw[s*32+t] = m;
  }

  // enc1
  {
    const int i = t>>3, c0 = (t&7)*16;
    float4 a0 = *(const float4*)(enc_b1+c0);
    float4 a1 = *(const float4*)(enc_b1+c0+4);
    float4 a2 = *(const float4*)(enc_b1+c0+8);
    float4 a3 = *(const float4*)(enc_b1+c0+12);
    for (int f=0; f<16; f++){
      const float xs = s_feats[i*16+f];
      const float* p = enc_w1 + f*128 + c0;
      a0 = fma4(a0, xs, *(const float4*)(p));
      a1 = fma4(a1, xs, *(const float4*)(p+4));
      a2 = fma4(a2, xs, *(const float4*)(p+8));
      a3 = fma4(a3, xs, *(const float4*)(p+12));
    }
    *(float4*)&s_h[i*132+c0]    = relu4(a0);
    *(float4*)&s_h[i*132+c0+4]  = relu4(a1);
    *(float4*)&s_h[i*132+c0+8]  = relu4(a2);
    *(float4*)&s_h[i*132+c0+12] = relu4(a3);
  }
  __syncthreads();

  // enc2 -> packed x + packed tap
  {
    const int i = t>>3, c0 = (t&7)*16;
    float4 a0 = *(const float4*)(enc_b2+c0);
    float4 a1 = *(const float4*)(enc_b2+c0+4);
    float4 a2 = *(const float4*)(enc_b2+c0+8);
    float4 a3 = *(const float4*)(enc_b2+c0+12);
    for (int k=0;k<128;k+=4){
      const float4 hv = *(const float4*)&s_h[i*132+k];
      #pragma unroll
      for (int kk=0;kk<4;kk++){
        const float* p = enc_w2 + (k+kk)*128 + c0;
        const float xs = comp4(hv,kk);
        a0 = fma4(a0, xs, *(const float4*)(p));
        a1 = fma4(a1, xs, *(const float4*)(p+4));
        a2 = fma4(a2, xs, *(const float4*)(p+8));
        a3 = fma4(a3, xs, *(const float4*)(p+12));
      }
    }
    a0 = relu4(a0); a1 = relu4(a1); a2 = relu4(a2); a3 = relu4(a3);
    const uint4 p0 = pack4(a0), p1 = pack4(a1), p2 = pack4(a2), p3 = pack4(a3);
    uint_t* xp = xpk + ((size_t)s*32 + i)*128;
    *(uint4*)&xp[c0]    = p0;
    *(uint4*)&xp[c0+4]  = p1;
    *(uint4*)&xp[c0+8]  = p2;
    *(uint4*)&xp[c0+12] = p3;
    if (i == s_ai){
      uint_t* xc = xcatpk + (size_t)s*1152;
      *(uint4*)&xc[c0]    = p0;
      *(uint4*)&xc[c0+4]  = p1;
      *(uint4*)&xc[c0+8]  = p2;
      *(uint4*)&xc[c0+12] = p3;
    }
  }
}

// =============== MFMA bf16x3 GEMM, two independent segments per launch ===============
// Segment 1: blocks [0, nblk1): A1 (stride astr1), B0/B1 split at ctsplit, C0/C1.
// Segment 2: blocks [nblk1, ...): A2 (stride astr2), B2 -> C2, nct2 col tiles.
// All C row strides = 512. Tile 64x64, 4 waves, 16x16x32 bf16 MFMA x3 (hi*hi+hi*lo+lo*hi).
template<int KD>
__global__ __launch_bounds__(256) void mfma_gemm(
    const uint_t* __restrict__ A1, int astr1,
    const ushort_t* __restrict__ B0hi, const ushort_t* __restrict__ B0lo,
    const ushort_t* __restrict__ B1hi, const ushort_t* __restrict__ B1lo,
    float* __restrict__ C0, float* __restrict__ C1,
    int nct1, int ctsplit, int nblk1,
    const uint_t* __restrict__ A2, int astr2,
    const ushort_t* __restrict__ B2hi, const ushort_t* __restrict__ B2lo,
    float* __restrict__ C2, int nct2)
{
  const int t = threadIdx.x;
  const int w = t>>6, lane = t&63;
  const int bid = blockIdx.x;
  const uint_t* Ap; int astr; const ushort_t* Bhi; const ushort_t* Blo; float* C; int cb, rt;
  if (bid < nblk1){
    rt = bid / nct1; const int ct = bid % nct1;
    Ap = A1; astr = astr1;
    if (ct < ctsplit){ Bhi = B0hi; Blo = B0lo; C = C0; cb = ct*64; }
    else             { Bhi = B1hi; Blo = B1lo; C = C1; cb = (ct-ctsplit)*64; }
  } else {
    const int u = bid - nblk1;
    rt = u / nct2; const int ct = u % nct2;
    Ap = A2; astr = astr2;
    Bhi = B2hi; Blo = B2lo; C = C2; cb = ct*64;
  }
  const int m = lane & 15, quad = lane >> 4;
  const int arow = rt*64 + w*16 + m;
  const uint_t* ap = Ap + (size_t)arow*astr + quad*8;
  floatx4 acc[4];
  #pragma unroll
  for (int i=0;i<4;i++) acc[i] = (floatx4){0.f,0.f,0.f,0.f};
  const ushort_t* bp0 = Bhi + (size_t)(cb +  0 + m)*KD + quad*8;
  const ushort_t* bp1 = Bhi + (size_t)(cb + 16 + m)*KD + quad*8;
  const ushort_t* bp2 = Bhi + (size_t)(cb + 32 + m)*KD + quad*8;
  const ushort_t* bp3 = Bhi + (size_t)(cb + 48 + m)*KD + quad*8;
  const size_t lod = (size_t)(Blo - Bhi);

  for (int k0=0; k0<KD; k0+=32){
    const uint4 ua0 = *(const uint4*)(ap);
    const uint4 ua1 = *(const uint4*)(ap+4);
    ap += 32;
    short8 ahi, alo;
    ahi[0]=(short)(ua0.x>>16); alo[0]=(short)(ua0.x);
    ahi[1]=(short)(ua0.y>>16); alo[1]=(short)(ua0.y);
    ahi[2]=(short)(ua0.z>>16); alo[2]=(short)(ua0.z);
    ahi[3]=(short)(ua0.w>>16); alo[3]=(short)(ua0.w);
    ahi[4]=(short)(ua1.x>>16); alo[4]=(short)(ua1.x);
    ahi[5]=(short)(ua1.y>>16); alo[5]=(short)(ua1.y);
    ahi[6]=(short)(ua1.z>>16); alo[6]=(short)(ua1.z);
    ahi[7]=(short)(ua1.w>>16); alo[7]=(short)(ua1.w);
    {
      const short8 bh = *(const short8*)(bp0);
      const short8 bl = *(const short8*)(bp0 + lod);
      acc[0] = __builtin_amdgcn_mfma_f32_16x16x32_bf16(ahi, bh, acc[0], 0,0,0);
      acc[0] = __builtin_amdgcn_mfma_f32_16x16x32_bf16(ahi, bl, acc[0], 0,0,0);
      acc[0] = __builtin_amdgcn_mfma_f32_16x16x32_bf16(alo, bh, acc[0], 0,0,0);
      bp0 += 32;
    }
    {
      const short8 bh = *(const short8*)(bp1);
      const short8 bl = *(const short8*)(bp1 + lod);
      acc[1] = __builtin_amdgcn_mfma_f32_16x16x32_bf16(ahi, bh, acc[1], 0,0,0);
      acc[1] = __builtin_amdgcn_mfma_f32_16x16x32_bf16(ahi, bl, acc[1], 0,0,0);
      acc[1] = __builtin_amdgcn_mfma_f32_16x16x32_bf16(alo, bh, acc[1], 0,0,0);
      bp1 += 32;
    }
    {
      const short8 bh = *(const short8*)(bp2);
      const short8 bl = *(const short8*)(bp2 + lod);
      acc[2] = __builtin_amdgcn_mfma_f32_16x16x32_bf16(ahi, bh, acc[2], 0,0,0);
      acc[2] = __builtin_amdgcn_mfma_f32_16x16x32_bf16(ahi, bl, acc[2], 0,0,0);
      acc[2] = __builtin_amdgcn_mfma_f32_16x16x32_bf16(alo, bh, acc[2], 0,0,0);
      bp2 += 32;
    }
    {
      const short8 bh = *(const short8*)(bp3);
      const short8 bl = *(const short8*)(bp3 + lod);
      acc[3] = __builtin_amdgcn_mfma_f32_16x16x32_bf16(ahi, bh, acc[3], 0,0,0);
      acc[3] = __builtin_amdgcn_mfma_f32_16x16x32_bf16(ahi, bl, acc[3], 0,0,0);
      acc[3] = __builtin_amdgcn_mfma_f32_16x16x32_bf16(alo, bh, acc[3], 0,0,0);
      bp3 += 32;
    }
  }
  const int crow0 = rt*64 + w*16 + quad*4;
  #pragma unroll
  for (int nt2=0; nt2<4; nt2++){
    const int col = cb + nt2*16 + m;
    #pragma unroll
    for (int r=0;r<4;r++)
      C[(size_t)(crow0 + r)*512 + col] = acc[nt2][r];
  }
}

// =============== K3: GAT layer-1 attention; x2 packed in place of gr + packed tap ===============
__global__ __launch_bounds__(256) void attn1_kernel(
    const float* __restrict__ gl, const float* __restrict__ gr, // [4096][512]
    const float* __restrict__ att, const float* __restrict__ bias,
    const unsigned* __restrict__ adjw, const int* __restrict__ aiw,
    uint_t* __restrict__ x2pk,    // aliases gr buffer (packed in place)
    uint_t* __restrict__ xcatpk)  // [128][1152] packed
{
  __shared__ __align__(16) float s_gl[32*132];
  __shared__ __align__(16) float s_gr[32*132];
  __shared__ __align__(16) float s_att[128];
  __shared__ __align__(16) float s_b[128];
  __shared__ float s_lg[32*33];
  __shared__ unsigned s_adj[32];
  const int t = threadIdx.x;
  const int s = blockIdx.x >> 2, h = blockIdx.x & 3;
  const float* glp = gl + (size_t)s*32*512 + h*128;
  const float* grp = gr + (size_t)s*32*512 + h*128;

  {
    const int i = t>>3, c0 = (t&7)*16;
    #pragma unroll
    for (int q=0;q<4;q++){
      *(float4*)&s_gl[i*132 + c0 + q*4] = *(const float4*)&glp[(size_t)i*512 + c0 + q*4];
      *(float4*)&s_gr[i*132 + c0 + q*4] = *(const float4*)&grp[(size_t)i*512 + c0 + q*4];
    }
  }
  if (t < 128){ s_att[t] = att[h*128 + t]; s_b[t] = bias[h*128 + t]; }
  if (t >= 224) s_adj[t-224] = adjw[s*32 + (t-224)];
  const int ai = aiw[s];
  __syncthreads();

  // logits
  {
    const int i = t>>3, jb = t&7;
    float acc[4] = {0.f,0.f,0.f,0.f};
    for (int c=0;c<128;c+=4){
      const float4 g = *(const float4*)&s_gr[i*132+c];
      const float4 a = *(const float4*)&s_att[c];
      #pragma unroll
      for (int mm=0;mm<4;mm++){
        const float4 gj = *(const float4*)&s_gl[(jb+8*mm)*132 + c];
        float ex = g.x+gj.x; ex = fmaxf(ex, 0.2f*ex);
        float ey = g.y+gj.y; ey = fmaxf(ey, 0.2f*ey);
        float ez = g.z+gj.z; ez = fmaxf(ez, 0.2f*ez);
        float ew = g.w+gj.w; ew = fmaxf(ew, 0.2f*ew);
        acc[mm] += ex*a.x + ey*a.y + ez*a.z + ew*a.w;
      }
    }
    #pragma unroll
    for (int mm=0;mm<4;mm++) s_lg[i*33 + jb + 8*mm] = acc[mm];
  }
  __syncthreads();

  // masked softmax
  for (int rnd=0; rnd<4; rnd++){
    const int i = rnd*8 + (t>>5), j = t&31;
    const float lg = s_lg[i*33+j];
    const bool ok = (s_adj[i]>>j)&1u;
    float v = ok ? lg : -3.0e38f;
    #pragma unroll
    for (int d_=16; d_; d_>>=1) v = fmaxf(v, __shfl_xor(v, d_, 32));
    const float e = ok ? __expf(lg - v) : 0.f;
    float sum = e;
    #pragma unroll
    for (int d_=16; d_; d_>>=1) sum += __shfl_xor(sum, d_, 32);
    s_lg[i*33+j] = e / sum;
  }
  __syncthreads();

  // aggregate -> packed x2 (in place) + packed tap
  {
    const int i = t>>3, c0 = (t&7)*16;
    float4 o0 = make_float4(0.f,0.f,0.f,0.f), o1 = o0, o2 = o0, o3 = o0;
    for (int j=0;j<32;j++){
      const float al = s_lg[i*33+j];
      o0 = fma4(o0, al, *(const float4*)&s_gl[j*132 + c0]);
      o1 = fma4(o1, al, *(const float4*)&s_gl[j*132 + c0 + 4]);
      o2 = fma4(o2, al, *(const float4*)&s_gl[j*132 + c0 + 8]);
      o3 = fma4(o3, al, *(const float4*)&s_gl[j*132 + c0 + 12]);
    }
    const float4 b0 = *(const float4*)&s_b[c0];
    const float4 b1 = *(const float4*)&s_b[c0+4];
    const float4 b2 = *(const float4*)&s_b[c0+8];
    const float4 b3 = *(const float4*)&s_b[c0+12];
    o0 = relu4(make_float4(o0.x+b0.x, o0.y+b0.y, o0.z+b0.z, o0.w+b0.w));
    o1 = relu4(make_float4(o1.x+b1.x, o1.y+b1.y, o1.z+b1.z, o1.w+b1.w));
    o2 = relu4(make_float4(o2.x+b2.x, o2.y+b2.y, o2.z+b2.z, o2.w+b2.w));
    o3 = relu4(make_float4(o3.x+b3.x, o3.y+b3.y, o3.z+b3.z, o3.w+b3.w));
    const uint4 p0 = pack4(o0), p1 = pack4(o1), p2 = pack4(o2), p3 = pack4(o3);
    uint_t* xp = x2pk + ((size_t)s*32 + i)*512 + h*128;
    *(uint4*)&xp[c0]    = p0;
    *(uint4*)&xp[c0+4]  = p1;
    *(uint4*)&xp[c0+8]  = p2;
    *(uint4*)&xp[c0+12] = p3;
    if (i == ai){
      uint_t* tp = xcatpk + (size_t)s*1152 + 128 + h*128;
      *(uint4*)&tp[c0]    = p0;
      *(uint4*)&tp[c0+4]  = p1;
      *(uint4*)&tp[c0+8]  = p2;
      *(uint4*)&tp[c0+12] = p3;
    }
  }
}

// =============== K6: attn2 (row ai only) + x3 -> packed xcat[640..1152] ===============
__global__ __launch_bounds__(256) void attn2_kernel(
    const float* __restrict__ gl2, const float* __restrict__ grt,
    const float* __restrict__ att2, const float* __restrict__ bias2,
    const unsigned* __restrict__ adjw, const int* __restrict__ aiw,
    uint_t* __restrict__ xcatpk)
{
  __shared__ __align__(16) float s_gl[32*132];
  __shared__ __align__(16) float s_gr[128];
  __shared__ __align__(16) float s_at[128];
  __shared__ __align__(16) float s_bb[128];
  __shared__ float s_lg[32];
  __shared__ float s_al[32];
  const int t = threadIdx.x;
  const int s = blockIdx.x >> 2, h = blockIdx.x & 3;
  const int ai = aiw[s];
  const unsigned arow = adjw[s*32+ai];
  {
    const int i = t>>3, c0 = (t&7)*16;
    const float* g0 = gl2 + ((size_t)(s*32+i))*512 + h*128;
    #pragma unroll
    for (int q=0;q<4;q++)
      *(float4*)&s_gl[i*132 + c0 + q*4] = *(const float4*)&g0[c0 + q*4];
  }
  if (t < 128) s_gr[t] = grt[(size_t)s*512 + h*128 + t];
  else { const int u=t-128; s_at[u] = att2[h*128+u]; s_bb[u] = bias2[h*128+u]; }
  __syncthreads();
  {
    const int j = t>>3, p = t&7;
    float sum = 0.f;
    #pragma unroll
    for (int q=0;q<4;q++){
      const int c = p*16 + q*4;
      const float4 g = *(const float4*)&s_gl[j*132 + c];
      const float4 r = *(const float4*)&s_gr[c];
      const float4 a = *(const float4*)&s_at[c];
      float e0 = r.x+g.x; e0 = fmaxf(e0, 0.2f*e0);
      float e1 = r.y+g.y; e1 = fmaxf(e1, 0.2f*e1);
      float e2 = r.z+g.z; e2 = fmaxf(e2, 0.2f*e2);
      float e3 = r.w+g.w; e3 = fmaxf(e3, 0.2f*e3);
      sum += e0*a.x + e1*a.y + e2*a.z + e3*a.w;
    }
    sum += __shfl_xor(sum,1,64);
    sum += __shfl_xor(sum,2,64);
    sum += __shfl_xor(sum,4,64);
    if (p==0) s_lg[j] = sum;
  }
  __syncthreads();
  if (t < 32){
    const float lg = s_lg[t];
    const bool ok = (arow>>t)&1u;
    float v = ok ? lg : -3.0e38f;
    #pragma unroll
    for (int d_=16; d_; d_>>=1) v = fmaxf(v, __shfl_xor(v, d_, 32));
    const float e = ok ? __expf(lg - v) : 0.f;
    float sm = e;
    #pragma unroll
    for (int d_=16; d_; d_>>=1) sm += __shfl_xor(sm, d_, 32);
    s_al[t] = e / sm;
  }
  __syncthreads();
  if (t < 128){
    float acc = 0.f;
    #pragma unroll 8
    for (int j=0;j<32;j++) acc += s_al[j] * s_gl[j*132 + t];
    xcatpk[(size_t)s*1152 + 640 + h*128 + t] = packbf(fmaxf(acc + s_bb[t], 0.f));
  }
}

// =============== K8: heads epilogue + final combine, block per sample ===============
__global__ __launch_bounds__(256) void heads2_kernel(
    const float* __restrict__ Ch,  // [128][512] = [hq|hv] pre-bias
    const float* __restrict__ q_b1, const float* __restrict__ q_w2, const float* __restrict__ q_b2,
    const float* __restrict__ v_b1, const float* __restrict__ v_w2, const float* __restrict__ v_b2,
    float* __restrict__ out)
{
  __shared__ float s_p[4*6];
  const int t = threadIdx.x, s = blockIdx.x;
  const float hq = fmaxf(Ch[(size_t)s*512 + t]       + q_b1[t], 0.f);
  const float hv = fmaxf(Ch[(size_t)s*512 + 256 + t] + v_b1[t], 0.f);
  float p[6];
  #pragma unroll
  for (int o=0;o<5;o++) p[o] = hq * q_w2[t*5+o];
  p[5] = hv * v_w2[t];
  #pragma unroll
  for (int d_=32; d_; d_>>=1){
    #pragma unroll
    for (int o=0;o<6;o++) p[o] += __shfl_xor(p[o], d_, 64);
  }
  const int w = t>>6, lane = t&63;
  if (lane==0){
    #pragma unroll
    for (int o=0;o<6;o++) s_p[w*6+o] = p[o];
  }
  __syncthreads();
  if (t < 6) s_p[t] = s_p[t] + s_p[6+t] + s_p[12+t] + s_p[18+t];
  __syncthreads();
  if (t < 5){
    const float q0 = s_p[0]+q_b2[0], q1 = s_p[1]+q_b2[1], q2 = s_p[2]+q_b2[2],
                q3 = s_p[3]+q_b2[3], q4 = s_p[4]+q_b2[4];
    const float mean = (q0+q1+q2+q3+q4) / 5.0f;
    const float v = s_p[5] + v_b2[0];
    const float qt = (t==0?q0:t==1?q1:t==2?q2:t==3?q3:q4);
    out[s*5+t] = qt - mean + v;
  }
}

extern "C" void kernel_launch(void* const* d_in, const int* in_sizes, int n_in,
                              void* d_out, int out_size, void* d_ws, size_t ws_size,
                              hipStream_t stream) {
  (void)n_in; (void)out_size; (void)ws_size;
  const float* obs    = (const float*)d_in[0];
  const float* enc_w1 = (const float*)d_in[1];
  const float* enc_b1 = (const float*)d_in[2];
  const float* enc_w2 = (const float*)d_in[3];
  const float* enc_b2 = (const float*)d_in[4];
  const float* wl1    = (const float*)d_in[5];
  const float* wr1    = (const float*)d_in[6];
  const float* att1   = (const float*)d_in[7];
  const float* bias1  = (const float*)d_in[8];
  const float* wl2    = (const float*)d_in[9];
  const float* wr2    = (const float*)d_in[10];
  const float* att2   = (const float*)d_in[11];
  const float* bias2  = (const float*)d_in[12];
  const float* q_w1   = (const float*)d_in[13];
  const float* q_b1   = (const float*)d_in[14];
  const float* q_w2   = (const float*)d_in[15];
  const float* q_b2   = (const float*)d_in[16];
  const float* v_w1   = (const float*)d_in[17];
  const float* v_b1   = (const float*)d_in[18];
  const float* v_w2   = (const float*)d_in[19];
  const float* v_b2   = (const float*)d_in[20];

  // workspace layout (bytes)
  char* ws = (char*)d_ws;
  uint_t*   x_pk    = (uint_t*)  (ws + 0);           // 2,097,152
  uint_t*   xcat_pk = (uint_t*)  (ws + 2097152);     //   589,824
  unsigned* adjw    = (unsigned*)(ws + 2686976);     //    16,384
  int*      aiw     = (int*)     (ws + 2703360);     //       512
  float*    gl_buf  = (float*)   (ws + 2703872);     // 8,388,608
  float*    gr_buf  = (float*)   (ws + 11092480);    // 8,388,608 (x2 packed in place later)
  ushort_t* wl1Thi  = (ushort_t*)(ws + 19481088);    //   131,072 each
  ushort_t* wl1Tlo  = (ushort_t*)(ws + 19612160);
  ushort_t* wr1Thi  = (ushort_t*)(ws + 19743232);
  ushort_t* wr1Tlo  = (ushort_t*)(ws + 19874304);
  ushort_t* wl2Thi  = (ushort_t*)(ws + 20005376);    //   524,288 each
  ushort_t* wl2Tlo  = (ushort_t*)(ws + 20529664);
  ushort_t* wr2Thi  = (ushort_t*)(ws + 21053952);
  ushort_t* wr2Tlo  = (ushort_t*)(ws + 21578240);
  ushort_t* qw1Thi  = (ushort_t*)(ws + 22102528);    //   589,824 each
  ushort_t* qw1Tlo  = (ushort_t*)(ws + 22692352);
  ushort_t* vw1Thi  = (ushort_t*)(ws + 23282176);
  ushort_t* vw1Tlo  = (ushort_t*)(ws + 23872000);
  float*    grt     = (float*)   (ws + 24461824);    //   262,144
  float*    headsC  = (float*)   (ws + 24723968);    //   262,144
  // end 24,986,112

  const int bs = in_sizes[0] / 577;   // 128

  // enc (128 blocks) + all weight converts (1216 blocks) fused
  prep_kernel<<<128 + 1216, 256, 0, stream>>>(obs, enc_w1, enc_b1, enc_w2, enc_b2,
      wl1, wr1, wl2, wr2, q_w1, v_w1,
      wl1Thi, wl1Tlo, wr1Thi, wr1Tlo, wl2Thi, wl2Tlo, wr2Thi, wr2Tlo,
      qw1Thi, qw1Tlo, vw1Thi, vw1Tlo,
      x_pk, xcat_pk, adjw, aiw);

  // proj1: gl1|gr1 = x @ [wl1|wr1]  (M=4096, K=128, N=512+512)
  mfma_gemm<128><<<1024, 256, 0, stream>>>(x_pk, 128,
      wl1Thi, wl1Tlo, wr1Thi, wr1Tlo, gl_buf, gr_buf, 16, 8, 1024,
      x_pk, 128, wl1Thi, wl1Tlo, gl_buf, 1);

  attn1_kernel<<<bs*4, 256, 0, stream>>>(gl_buf, gr_buf, att1, bias1, adjw, aiw,
                                         (uint_t*)gr_buf, xcat_pk);

  // proj2 (512 blocks): gl2 = x2 @ wl2 ; fused grtap (16 blocks): grt = x2tap @ wr2
  mfma_gemm<512><<<512 + 16, 256, 0, stream>>>((const uint_t*)gr_buf, 512,
      wl2Thi, wl2Tlo, wl2Thi, wl2Tlo, gl_buf, gl_buf, 8, 8, 512,
      xcat_pk + 128, 1152, wr2Thi, wr2Tlo, grt, 8);

  attn2_kernel<<<bs*4, 256, 0, stream>>>(gl_buf, grt, att2, bias2, adjw, aiw, xcat_pk);

  // heads GEMM: [hq|hv] = xcat @ [q_w1|v_w1]  (M=128, K=1152, N=256+256)
  mfma_gemm<1152><<<16, 256, 0, stream>>>(xcat_pk, 1152,
      qw1Thi, qw1Tlo, vw1Thi, vw1Tlo, headsC, headsC + 256, 8, 4, 16,
      xcat_pk, 1152, qw1Thi, qw1Tlo, headsC, 1);

  heads2_kernel<<<bs, 256, 0, stream>>>(headsC, q_b1, q_w2, q_b2, v_b1, v_w2, v_b2,
                                        (float*)d_out);
}

// Round 8
// 239.201 us; speedup vs baseline: 1.1957x; 1.1957x over previous
//
#include <hip/hip_runtime.h>
#include <hip/hip_bf16.h>

typedef unsigned int uint_t;
typedef unsigned short ushort_t;
typedef __attribute__((ext_vector_type(8))) short short8;
typedef __attribute__((ext_vector_type(4))) float floatx4;

__device__ __forceinline__ float4 fma4(float4 a, float s, float4 w){
  a.x += s*w.x; a.y += s*w.y; a.z += s*w.z; a.w += s*w.w; return a;
}
__device__ __forceinline__ float4 relu4(float4 a){
  return make_float4(fmaxf(a.x,0.f),fmaxf(a.y,0.f),fmaxf(a.z,0.f),fmaxf(a.w,0.f));
}
__device__ __forceinline__ float comp4(float4 v, int k){
  return k==0? v.x : k==1? v.y : k==2? v.z : v.w;
}
__device__ __forceinline__ unsigned bf16rne(float f){
  unsigned u = __float_as_uint(f);
  return (u + 0x7fffu + ((u>>16)&1u)) >> 16;
}
__device__ __forceinline__ uint_t packbf(float f){
  unsigned hb = bf16rne(f);
  float hf = __uint_as_float(hb<<16);
  unsigned lb = bf16rne(f - hf);
  return (hb<<16) | lb;
}
__device__ __forceinline__ uint4 pack4(float4 v){
  uint4 u; u.x=packbf(v.x); u.y=packbf(v.y); u.z=packbf(v.z); u.w=packbf(v.w); return u;
}

// Fragment-order offset (elements): rows/cols grouped by 16, k by 32.
// off(n,k) = (n>>4)*16*K + (k>>5)*512 + (n&15)*32 + (k&31)

// =============== K1 fused: enc (blocks 0..127) + weight convert (blocks 128..1343) ===============
__global__ __launch_bounds__(256) void prep_kernel(
    const float* __restrict__ obs,
    const float* __restrict__ enc_w1, const float* __restrict__ enc_b1,
    const float* __restrict__ enc_w2, const float* __restrict__ enc_b2,
    const float* __restrict__ wl1, const float* __restrict__ wr1,
    const float* __restrict__ wl2, const float* __restrict__ wr2,
    const float* __restrict__ q_w1, const float* __restrict__ v_w1,
    ushort_t* __restrict__ wl1Thi, ushort_t* __restrict__ wl1Tlo,
    ushort_t* __restrict__ wr1Thi, ushort_t* __restrict__ wr1Tlo,
    ushort_t* __restrict__ wl2Thi, ushort_t* __restrict__ wl2Tlo,
    ushort_t* __restrict__ wr2Thi, ushort_t* __restrict__ wr2Tlo,
    ushort_t* __restrict__ qw1Thi, ushort_t* __restrict__ qw1Tlo,
    ushort_t* __restrict__ vw1Thi, ushort_t* __restrict__ vw1Tlo,
    uint_t* __restrict__ xpk,     // fragment order, K=128
    uint_t* __restrict__ xcatpk,  // fragment order, K=1152, M=128
    unsigned* __restrict__ adjw, int* __restrict__ aiw)
{
  const int t = threadIdx.x, bid = blockIdx.x;
  if (bid >= 128){
    __shared__ float sm[32][33];
    const int cw = bid - 128;
    const float* in; ushort_t* ohi; ushort_t* olo; int K, N, tt;
    if (cw < 64)        { in=wl1;  ohi=wl1Thi; olo=wl1Tlo; K=128;  N=512; tt=cw; }
    else if (cw < 128)  { in=wr1;  ohi=wr1Thi; olo=wr1Tlo; K=128;  N=512; tt=cw-64; }
    else if (cw < 384)  { in=wl2;  ohi=wl2Thi; olo=wl2Tlo; K=512;  N=512; tt=cw-128; }
    else if (cw < 640)  { in=wr2;  ohi=wr2Thi; olo=wr2Tlo; K=512;  N=512; tt=cw-384; }
    else if (cw < 928)  { in=q_w1; ohi=qw1Thi; olo=qw1Tlo; K=1152; N=256; tt=cw-640; }
    else                { in=v_w1; ohi=vw1Thi; olo=vw1Tlo; K=1152; N=256; tt=cw-928; }
    const int ktiles = K>>5;
    const int kt = tt % ktiles, nt = tt / ktiles;
    const int r = t>>5, c = t&31;
    #pragma unroll
    for (int i=0;i<4;i++)
      sm[r+i*8][c] = in[(size_t)(kt*32 + r + i*8)*N + nt*32 + c];
    __syncthreads();
    #pragma unroll
    for (int i=0;i<4;i++){
      const int nl = r + i*8;
      const int n  = nt*32 + nl;
      const float f = sm[c][nl];
      const unsigned hb = bf16rne(f);
      const float hf = __uint_as_float(hb<<16);
      const unsigned lb = bf16rne(f - hf);
      const size_t off = (size_t)(n>>4)*(16*K) + (size_t)kt*512 + (size_t)(n&15)*32 + c;
      ohi[off] = (ushort_t)hb;
      olo[off] = (ushort_t)lb;
    }
    return;
  }
  // ---------------- encoder + adjacency + x1 tap ----------------
  __shared__ float s_pos[64];
  __shared__ float s_feats[512];
  __shared__ __align__(16) float s_h[32*132];
  __shared__ int s_ai;
  const int s = bid;
  const float* ob = obs + s*577;

  if (t < 64) s_pos[t] = ob[(t>>1)*18 + (t&1)];
  for (int e=t; e<512; e+=256){ const int i=e>>4, f=e&15; s_feats[e] = ob[i*18+2+f]; }
  if (t==0){
    float a = ob[576];
    a = fminf(fmaxf(a, 0.f), 31.f);
    const int ai = (int)a;
    s_ai = ai; aiw[s] = ai;
  }
  __syncthreads();

  if (t < 32){
    const float px = s_pos[2*t], py = s_pos[2*t+1];
    const float R2 = 0.09f;
    unsigned m = 0u;
    for (int j=0;j<32;j++){
      const float dx = __fsub_rn(px, s_pos[2*j]), dy = __fsub_rn(py, s_pos[2*j+1]);
      const float d2 = __fadd_rn(__fmul_rn(dx,dx), __fmul_rn(dy,dy));
      if (d2 <= R2 || j==t) m |= (1u<<j);
    }
    adjw[s*32+t] = m;
  }

  // enc1
  {
    const int i = t>>3, c0 = (t&7)*16;
    float4 a0 = *(const float4*)(enc_b1+c0);
    float4 a1 = *(const float4*)(enc_b1+c0+4);
    float4 a2 = *(const float4*)(enc_b1+c0+8);
    float4 a3 = *(const float4*)(enc_b1+c0+12);
    for (int f=0; f<16; f++){
      const float xs = s_feats[i*16+f];
      const float* p = enc_w1 + f*128 + c0;
      a0 = fma4(a0, xs, *(const float4*)(p));
      a1 = fma4(a1, xs, *(const float4*)(p+4));
      a2 = fma4(a2, xs, *(const float4*)(p+8));
      a3 = fma4(a3, xs, *(const float4*)(p+12));
    }
    *(float4*)&s_h[i*132+c0]    = relu4(a0);
    *(float4*)&s_h[i*132+c0+4]  = relu4(a1);
    *(float4*)&s_h[i*132+c0+8]  = relu4(a2);
    *(float4*)&s_h[i*132+c0+12] = relu4(a3);
  }
  __syncthreads();

  // enc2 -> fragment-order packed x + packed tap
  {
    const int i = t>>3, c0 = (t&7)*16;
    float4 a0 = *(const float4*)(enc_b2+c0);
    float4 a1 = *(const float4*)(enc_b2+c0+4);
    float4 a2 = *(const float4*)(enc_b2+c0+8);
    float4 a3 = *(const float4*)(enc_b2+c0+12);
    for (int k=0;k<128;k+=4){
      const float4 hv = *(const float4*)&s_h[i*132+k];
      #pragma unroll
      for (int kk=0;kk<4;kk++){
        const float* p = enc_w2 + (k+kk)*128 + c0;
        const float xs = comp4(hv,kk);
        a0 = fma4(a0, xs, *(const float4*)(p));
        a1 = fma4(a1, xs, *(const float4*)(p+4));
        a2 = fma4(a2, xs, *(const float4*)(p+8));
        a3 = fma4(a3, xs, *(const float4*)(p+12));
      }
    }
    a0 = relu4(a0); a1 = relu4(a1); a2 = relu4(a2); a3 = relu4(a3);
    const uint4 p0 = pack4(a0), p1 = pack4(a1), p2 = pack4(a2), p3 = pack4(a3);
    // x_pk fragment order, K=128: row = s*32+i
    uint_t* xp = xpk + (size_t)(s*2 + (i>>4))*2048 + (c0>>5)*512 + (i&15)*32 + (c0&31);
    *(uint4*)&xp[0]  = p0;
    *(uint4*)&xp[4]  = p1;
    *(uint4*)&xp[8]  = p2;
    *(uint4*)&xp[12] = p3;
    if (i == s_ai){
      // xcat fragment order, K=1152: row = s, k = c0..c0+15
      uint_t* xc = xcatpk + (size_t)(s>>4)*18432 + (c0>>5)*512 + (s&15)*32 + (c0&31);
      *(uint4*)&xc[0]  = p0;
      *(uint4*)&xc[4]  = p1;
      *(uint4*)&xc[8]  = p2;
      *(uint4*)&xc[12] = p3;
    }
  }
}

// =============== MFMA bf16x3 GEMM, fragment-order A and B, two segments ===============
// rbs = rowblock stride in uints (= 16*K_layout). B in fragment order (K = KD).
template<int KD>
__global__ __launch_bounds__(256) void mfma_gemm(
    const uint_t* __restrict__ A1, int rbs1,
    const ushort_t* __restrict__ B0hi, const ushort_t* __restrict__ B0lo,
    const ushort_t* __restrict__ B1hi, const ushort_t* __restrict__ B1lo,
    float* __restrict__ C0, float* __restrict__ C1,
    int nct1, int ctsplit, int nblk1,
    const uint_t* __restrict__ A2, int rbs2,
    const ushort_t* __restrict__ B2hi, const ushort_t* __restrict__ B2lo,
    float* __restrict__ C2, int nct2)
{
  const int t = threadIdx.x;
  const int w = t>>6, lane = t&63;
  const int m = lane & 15, quad = lane >> 4;
  const int bid = blockIdx.x;
  const uint_t* Ap; int rbs; const ushort_t* Bhi; const ushort_t* Blo; float* C; int cb, rt;
  if (bid < nblk1){
    rt = bid / nct1; const int ct = bid % nct1;
    Ap = A1; rbs = rbs1;
    if (ct < ctsplit){ Bhi = B0hi; Blo = B0lo; C = C0; cb = ct*64; }
    else             { Bhi = B1hi; Blo = B1lo; C = C1; cb = (ct-ctsplit)*64; }
  } else {
    const int u = bid - nblk1;
    rt = u / nct2; const int ct = u % nct2;
    Ap = A2; rbs = rbs2;
    Bhi = B2hi; Blo = B2lo; C = C2; cb = ct*64;
  }
  const uint_t* ap = Ap + (size_t)(rt*4 + w)*rbs + m*32 + quad*8;
  const ushort_t* bp0 = Bhi + (size_t)((cb>>4)+0)*(16*KD) + m*32 + quad*8;
  const ushort_t* bp1 = Bhi + (size_t)((cb>>4)+1)*(16*KD) + m*32 + quad*8;
  const ushort_t* bp2 = Bhi + (size_t)((cb>>4)+2)*(16*KD) + m*32 + quad*8;
  const ushort_t* bp3 = Bhi + (size_t)((cb>>4)+3)*(16*KD) + m*32 + quad*8;
  const size_t lod = (size_t)(Blo - Bhi);
  floatx4 acc[4];
  #pragma unroll
  for (int i=0;i<4;i++) acc[i] = (floatx4){0.f,0.f,0.f,0.f};

  for (int kc=0; kc<KD/32; kc++){
    const uint4 ua0 = *(const uint4*)(ap);
    const uint4 ua1 = *(const uint4*)(ap+4);
    ap += 512;
    short8 ahi, alo;
    ahi[0]=(short)(ua0.x>>16); alo[0]=(short)(ua0.x);
    ahi[1]=(short)(ua0.y>>16); alo[1]=(short)(ua0.y);
    ahi[2]=(short)(ua0.z>>16); alo[2]=(short)(ua0.z);
    ahi[3]=(short)(ua0.w>>16); alo[3]=(short)(ua0.w);
    ahi[4]=(short)(ua1.x>>16); alo[4]=(short)(ua1.x);
    ahi[5]=(short)(ua1.y>>16); alo[5]=(short)(ua1.y);
    ahi[6]=(short)(ua1.z>>16); alo[6]=(short)(ua1.z);
    ahi[7]=(short)(ua1.w>>16); alo[7]=(short)(ua1.w);
    {
      const short8 bh = *(const short8*)(bp0);
      const short8 bl = *(const short8*)(bp0 + lod);
      acc[0] = __builtin_amdgcn_mfma_f32_16x16x32_bf16(ahi, bh, acc[0], 0,0,0);
      acc[0] = __builtin_amdgcn_mfma_f32_16x16x32_bf16(ahi, bl, acc[0], 0,0,0);
      acc[0] = __builtin_amdgcn_mfma_f32_16x16x32_bf16(alo, bh, acc[0], 0,0,0);
      bp0 += 512;
    }
    {
      const short8 bh = *(const short8*)(bp1);
      const short8 bl = *(const short8*)(bp1 + lod);
      acc[1] = __builtin_amdgcn_mfma_f32_16x16x32_bf16(ahi, bh, acc[1], 0,0,0);
      acc[1] = __builtin_amdgcn_mfma_f32_16x16x32_bf16(ahi, bl, acc[1], 0,0,0);
      acc[1] = __builtin_amdgcn_mfma_f32_16x16x32_bf16(alo, bh, acc[1], 0,0,0);
      bp1 += 512;
    }
    {
      const short8 bh = *(const short8*)(bp2);
      const short8 bl = *(const short8*)(bp2 + lod);
      acc[2] = __builtin_amdgcn_mfma_f32_16x16x32_bf16(ahi, bh, acc[2], 0,0,0);
      acc[2] = __builtin_amdgcn_mfma_f32_16x16x32_bf16(ahi, bl, acc[2], 0,0,0);
      acc[2] = __builtin_amdgcn_mfma_f32_16x16x32_bf16(alo, bh, acc[2], 0,0,0);
      bp2 += 512;
    }
    {
      const short8 bh = *(const short8*)(bp3);
      const short8 bl = *(const short8*)(bp3 + lod);
      acc[3] = __builtin_amdgcn_mfma_f32_16x16x32_bf16(ahi, bh, acc[3], 0,0,0);
      acc[3] = __builtin_amdgcn_mfma_f32_16x16x32_bf16(ahi, bl, acc[3], 0,0,0);
      acc[3] = __builtin_amdgcn_mfma_f32_16x16x32_bf16(alo, bh, acc[3], 0,0,0);
      bp3 += 512;
    }
  }
  const int crow0 = rt*64 + w*16 + quad*4;
  #pragma unroll
  for (int nt2=0; nt2<4; nt2++){
    const int col = cb + nt2*16 + m;
    #pragma unroll
    for (int r=0;r<4;r++)
      C[(size_t)(crow0 + r)*512 + col] = acc[nt2][r];
  }
}

// =============== K3: GAT layer-1 attention; x2 -> fragment-order packed buffer + tap ===============
__global__ __launch_bounds__(256) void attn1_kernel(
    const float* __restrict__ gl, const float* __restrict__ gr, // [4096][512] row-major
    const float* __restrict__ att, const float* __restrict__ bias,
    const unsigned* __restrict__ adjw, const int* __restrict__ aiw,
    uint_t* __restrict__ x2pk,    // fragment order K=512 (separate buffer!)
    uint_t* __restrict__ xcatpk)  // fragment order K=1152
{
  __shared__ __align__(16) float s_gl[32*132];
  __shared__ __align__(16) float s_gr[32*132];
  __shared__ __align__(16) float s_att[128];
  __shared__ __align__(16) float s_b[128];
  __shared__ float s_lg[32*33];
  __shared__ unsigned s_adj[32];
  const int t = threadIdx.x;
  const int s = blockIdx.x >> 2, h = blockIdx.x & 3;
  const float* glp = gl + (size_t)s*32*512 + h*128;
  const float* grp = gr + (size_t)s*32*512 + h*128;

  {
    const int i = t>>3, c0 = (t&7)*16;
    #pragma unroll
    for (int q=0;q<4;q++){
      *(float4*)&s_gl[i*132 + c0 + q*4] = *(const float4*)&glp[(size_t)i*512 + c0 + q*4];
      *(float4*)&s_gr[i*132 + c0 + q*4] = *(const float4*)&grp[(size_t)i*512 + c0 + q*4];
    }
  }
  if (t < 128){ s_att[t] = att[h*128 + t]; s_b[t] = bias[h*128 + t]; }
  if (t >= 224) s_adj[t-224] = adjw[s*32 + (t-224)];
  const int ai = aiw[s];
  __syncthreads();

  // logits
  {
    const int i = t>>3, jb = t&7;
    float acc[4] = {0.f,0.f,0.f,0.f};
    for (int c=0;c<128;c+=4){
      const float4 g = *(const float4*)&s_gr[i*132+c];
      const float4 a = *(const float4*)&s_att[c];
      #pragma unroll
      for (int mm=0;mm<4;mm++){
        const float4 gj = *(const float4*)&s_gl[(jb+8*mm)*132 + c];
        float ex = g.x+gj.x; ex = fmaxf(ex, 0.2f*ex);
        float ey = g.y+gj.y; ey = fmaxf(ey, 0.2f*ey);
        float ez = g.z+gj.z; ez = fmaxf(ez, 0.2f*ez);
        float ew = g.w+gj.w; ew = fmaxf(ew, 0.2f*ew);
        acc[mm] += ex*a.x + ey*a.y + ez*a.z + ew*a.w;
      }
    }
    #pragma unroll
    for (int mm=0;mm<4;mm++) s_lg[i*33 + jb + 8*mm] = acc[mm];
  }
  __syncthreads();

  // masked softmax
  for (int rnd=0; rnd<4; rnd++){
    const int i = rnd*8 + (t>>5), j = t&31;
    const float lg = s_lg[i*33+j];
    const bool ok = (s_adj[i]>>j)&1u;
    float v = ok ? lg : -3.0e38f;
    #pragma unroll
    for (int d_=16; d_; d_>>=1) v = fmaxf(v, __shfl_xor(v, d_, 32));
    const float e = ok ? __expf(lg - v) : 0.f;
    float sum = e;
    #pragma unroll
    for (int d_=16; d_; d_>>=1) sum += __shfl_xor(sum, d_, 32);
    s_lg[i*33+j] = e / sum;
  }
  __syncthreads();

  // aggregate -> fragment-order packed x2 + tap
  {
    const int i = t>>3, c0 = (t&7)*16;
    float4 o0 = make_float4(0.f,0.f,0.f,0.f), o1 = o0, o2 = o0, o3 = o0;
    for (int j=0;j<32;j++){
      const float al = s_lg[i*33+j];
      o0 = fma4(o0, al, *(const float4*)&s_gl[j*132 + c0]);
      o1 = fma4(o1, al, *(const float4*)&s_gl[j*132 + c0 + 4]);
      o2 = fma4(o2, al, *(const float4*)&s_gl[j*132 + c0 + 8]);
      o3 = fma4(o3, al, *(const float4*)&s_gl[j*132 + c0 + 12]);
    }
    const float4 b0 = *(const float4*)&s_b[c0];
    const float4 b1 = *(const float4*)&s_b[c0+4];
    const float4 b2 = *(const float4*)&s_b[c0+8];
    const float4 b3 = *(const float4*)&s_b[c0+12];
    o0 = relu4(make_float4(o0.x+b0.x, o0.y+b0.y, o0.z+b0.z, o0.w+b0.w));
    o1 = relu4(make_float4(o1.x+b1.x, o1.y+b1.y, o1.z+b1.z, o1.w+b1.w));
    o2 = relu4(make_float4(o2.x+b2.x, o2.y+b2.y, o2.z+b2.z, o2.w+b2.w));
    o3 = relu4(make_float4(o3.x+b3.x, o3.y+b3.y, o3.z+b3.z, o3.w+b3.w));
    const uint4 p0 = pack4(o0), p1 = pack4(o1), p2 = pack4(o2), p3 = pack4(o3);
    // x2 fragment order, K=512: row = s*32+i, k = h*128+c0 .. +15
    const int kb = h*128 + c0;
    uint_t* xp = x2pk + (size_t)(s*2 + (i>>4))*8192 + (kb>>5)*512 + (i&15)*32 + (kb&31);
    *(uint4*)&xp[0]  = p0;
    *(uint4*)&xp[4]  = p1;
    *(uint4*)&xp[8]  = p2;
    *(uint4*)&xp[12] = p3;
    if (i == ai){
      // xcat fragment order, K=1152: row = s, k = 128 + h*128 + c0
      const int kk = 128 + kb;
      uint_t* tp = xcatpk + (size_t)(s>>4)*18432 + (kk>>5)*512 + (s&15)*32 + (kk&31);
      *(uint4*)&tp[0]  = p0;
      *(uint4*)&tp[4]  = p1;
      *(uint4*)&tp[8]  = p2;
      *(uint4*)&tp[12] = p3;
    }
  }
}

// =============== K6: attn2 (row ai only) + x3 -> fragment-order packed xcat ===============
__global__ __launch_bounds__(256) void attn2_kernel(
    const float* __restrict__ gl2, const float* __restrict__ grt,
    const float* __restrict__ att2, const float* __restrict__ bias2,
    const unsigned* __restrict__ adjw, const int* __restrict__ aiw,
    uint_t* __restrict__ xcatpk)
{
  __shared__ __align__(16) float s_gl[32*132];
  __shared__ __align__(16) float s_gr[128];
  __shared__ __align__(16) float s_at[128];
  __shared__ __align__(16) float s_bb[128];
  __shared__ float s_lg[32];
  __shared__ float s_al[32];
  const int t = threadIdx.x;
  const int s = blockIdx.x >> 2, h = blockIdx.x & 3;
  const int ai = aiw[s];
  const unsigned arow = adjw[s*32+ai];
  {
    const int i = t>>3, c0 = (t&7)*16;
    const float* g0 = gl2 + ((size_t)(s*32+i))*512 + h*128;
    #pragma unroll
    for (int q=0;q<4;q++)
      *(float4*)&s_gl[i*132 + c0 + q*4] = *(const float4*)&g0[c0 + q*4];
  }
  if (t < 128) s_gr[t] = grt[(size_t)s*512 + h*128 + t];
  else { const int u=t-128; s_at[u] = att2[h*128+u]; s_bb[u] = bias2[h*128+u]; }
  __syncthreads();
  {
    const int j = t>>3, p = t&7;
    float sum = 0.f;
    #pragma unroll
    for (int q=0;q<4;q++){
      const int c = p*16 + q*4;
      const float4 g = *(const float4*)&s_gl[j*132 + c];
      const float4 r = *(const float4*)&s_gr[c];
      const float4 a = *(const float4*)&s_at[c];
      float e0 = r.x+g.x; e0 = fmaxf(e0, 0.2f*e0);
      float e1 = r.y+g.y; e1 = fmaxf(e1, 0.2f*e1);
      float e2 = r.z+g.z; e2 = fmaxf(e2, 0.2f*e2);
      float e3 = r.w+g.w; e3 = fmaxf(e3, 0.2f*e3);
      sum += e0*a.x + e1*a.y + e2*a.z + e3*a.w;
    }
    sum += __shfl_xor(sum,1,64);
    sum += __shfl_xor(sum,2,64);
    sum += __shfl_xor(sum,4,64);
    if (p==0) s_lg[j] = sum;
  }
  __syncthreads();
  if (t < 32){
    const float lg = s_lg[t];
    const bool ok = (arow>>t)&1u;
    float v = ok ? lg : -3.0e38f;
    #pragma unroll
    for (int d_=16; d_; d_>>=1) v = fmaxf(v, __shfl_xor(v, d_, 32));
    const float e = ok ? __expf(lg - v) : 0.f;
    float sm = e;
    #pragma unroll
    for (int d_=16; d_; d_>>=1) sm += __shfl_xor(sm, d_, 32);
    s_al[t] = e / sm;
  }
  __syncthreads();
  if (t < 128){
    float acc = 0.f;
    #pragma unroll 8
    for (int j=0;j<32;j++) acc += s_al[j] * s_gl[j*132 + t];
    const int kk = 640 + h*128 + t;
    xcatpk[(size_t)(s>>4)*18432 + (kk>>5)*512 + (s&15)*32 + (kk&31)]
        = packbf(fmaxf(acc + s_bb[t], 0.f));
  }
}

// =============== K8: heads epilogue + final combine, block per sample ===============
__global__ __launch_bounds__(256) void heads2_kernel(
    const float* __restrict__ Ch,  // [128][512] = [hq|hv] pre-bias
    const float* __restrict__ q_b1, const float* __restrict__ q_w2, const float* __restrict__ q_b2,
    const float* __restrict__ v_b1, const float* __restrict__ v_w2, const float* __restrict__ v_b2,
    float* __restrict__ out)
{
  __shared__ float s_p[4*6];
  const int t = threadIdx.x, s = blockIdx.x;
  const float hq = fmaxf(Ch[(size_t)s*512 + t]       + q_b1[t], 0.f);
  const float hv = fmaxf(Ch[(size_t)s*512 + 256 + t] + v_b1[t], 0.f);
  float p[6];
  #pragma unroll
  for (int o=0;o<5;o++) p[o] = hq * q_w2[t*5+o];
  p[5] = hv * v_w2[t];
  #pragma unroll
  for (int d_=32; d_; d_>>=1){
    #pragma unroll
    for (int o=0;o<6;o++) p[o] += __shfl_xor(p[o], d_, 64);
  }
  const int w = t>>6, lane = t&63;
  if (lane==0){
    #pragma unroll
    for (int o=0;o<6;o++) s_p[w*6+o] = p[o];
  }
  __syncthreads();
  if (t < 6) s_p[t] = s_p[t] + s_p[6+t] + s_p[12+t] + s_p[18+t];
  __syncthreads();
  if (t < 5){
    const float q0 = s_p[0]+q_b2[0], q1 = s_p[1]+q_b2[1], q2 = s_p[2]+q_b2[2],
                q3 = s_p[3]+q_b2[3], q4 = s_p[4]+q_b2[4];
    const float mean = (q0+q1+q2+q3+q4) / 5.0f;
    const float v = s_p[5] + v_b2[0];
    const float qt = (t==0?q0:t==1?q1:t==2?q2:t==3?q3:q4);
    out[s*5+t] = qt - mean + v;
  }
}

extern "C" void kernel_launch(void* const* d_in, const int* in_sizes, int n_in,
                              void* d_out, int out_size, void* d_ws, size_t ws_size,
                              hipStream_t stream) {
  (void)n_in; (void)out_size; (void)ws_size;
  const float* obs    = (const float*)d_in[0];
  const float* enc_w1 = (const float*)d_in[1];
  const float* enc_b1 = (const float*)d_in[2];
  const float* enc_w2 = (const float*)d_in[3];
  const float* enc_b2 = (const float*)d_in[4];
  const float* wl1    = (const float*)d_in[5];
  const float* wr1    = (const float*)d_in[6];
  const float* att1   = (const float*)d_in[7];
  const float* bias1  = (const float*)d_in[8];
  const float* wl2    = (const float*)d_in[9];
  const float* wr2    = (const float*)d_in[10];
  const float* att2   = (const float*)d_in[11];
  const float* bias2  = (const float*)d_in[12];
  const float* q_w1   = (const float*)d_in[13];
  const float* q_b1   = (const float*)d_in[14];
  const float* q_w2   = (const float*)d_in[15];
  const float* q_b2   = (const float*)d_in[16];
  const float* v_w1   = (const float*)d_in[17];
  const float* v_b1   = (const float*)d_in[18];
  const float* v_w2   = (const float*)d_in[19];
  const float* v_b2   = (const float*)d_in[20];

  // workspace layout (bytes)
  char* ws = (char*)d_ws;
  uint_t*   x_pk    = (uint_t*)  (ws + 0);           // 2,097,152
  uint_t*   xcat_pk = (uint_t*)  (ws + 2097152);     //   589,824
  unsigned* adjw    = (unsigned*)(ws + 2686976);     //    16,384
  int*      aiw     = (int*)     (ws + 2703360);     //       512
  float*    gl_buf  = (float*)   (ws + 2703872);     // 8,388,608
  float*    gr_buf  = (float*)   (ws + 11092480);    // 8,388,608
  ushort_t* wl1Thi  = (ushort_t*)(ws + 19481088);    //   131,072 each
  ushort_t* wl1Tlo  = (ushort_t*)(ws + 19612160);
  ushort_t* wr1Thi  = (ushort_t*)(ws + 19743232);
  ushort_t* wr1Tlo  = (ushort_t*)(ws + 19874304);
  ushort_t* wl2Thi  = (ushort_t*)(ws + 20005376);    //   524,288 each
  ushort_t* wl2Tlo  = (ushort_t*)(ws + 20529664);
  ushort_t* wr2Thi  = (ushort_t*)(ws + 21053952);
  ushort_t* wr2Tlo  = (ushort_t*)(ws + 21578240);
  ushort_t* qw1Thi  = (ushort_t*)(ws + 22102528);    //   589,824 each
  ushort_t* qw1Tlo  = (ushort_t*)(ws + 22692352);
  ushort_t* vw1Thi  = (ushort_t*)(ws + 23282176);
  ushort_t* vw1Tlo  = (ushort_t*)(ws + 23872000);
  float*    grt     = (float*)   (ws + 24461824);    //   262,144
  float*    headsC  = (float*)   (ws + 24723968);    //   262,144
  uint_t*   x2_pk   = (uint_t*)  (ws + 24986112);    // 8,388,608
  // end 33,374,720

  const int bs = in_sizes[0] / 577;   // 128

  prep_kernel<<<128 + 1216, 256, 0, stream>>>(obs, enc_w1, enc_b1, enc_w2, enc_b2,
      wl1, wr1, wl2, wr2, q_w1, v_w1,
      wl1Thi, wl1Tlo, wr1Thi, wr1Tlo, wl2Thi, wl2Tlo, wr2Thi, wr2Tlo,
      qw1Thi, qw1Tlo, vw1Thi, vw1Tlo,
      x_pk, xcat_pk, adjw, aiw);

  // proj1: gl1|gr1 = x @ [wl1|wr1]  (M=4096, K=128, N=512+512)
  mfma_gemm<128><<<1024, 256, 0, stream>>>(x_pk, 2048,
      wl1Thi, wl1Tlo, wr1Thi, wr1Tlo, gl_buf, gr_buf, 16, 8, 1024,
      x_pk, 2048, wl1Thi, wl1Tlo, gl_buf, 1);

  attn1_kernel<<<bs*4, 256, 0, stream>>>(gl_buf, gr_buf, att1, bias1, adjw, aiw,
                                         x2_pk, xcat_pk);

  // proj2 (512 blocks): gl2 = x2 @ wl2 ; fused grtap (16 blocks): grt = x2tap @ wr2
  mfma_gemm<512><<<512 + 16, 256, 0, stream>>>(x2_pk, 8192,
      wl2Thi, wl2Tlo, wl2Thi, wl2Tlo, gl_buf, gl_buf, 8, 8, 512,
      xcat_pk + 2048, 18432, wr2Thi, wr2Tlo, grt, 8);

  attn2_kernel<<<bs*4, 256, 0, stream>>>(gl_buf, grt, att2, bias2, adjw, aiw, xcat_pk);

  // heads GEMM: [hq|hv] = xcat @ [q_w1|v_w1]  (M=128, K=1152, N=256+256)
  mfma_gemm<1152><<<16, 256, 0, stream>>>(xcat_pk, 18432,
      qw1Thi, qw1Tlo, vw1Thi, vw1Tlo, headsC, headsC + 256, 8, 4, 16,
      xcat_pk, 18432, qw1Thi, qw1Tlo, headsC, 1);

  heads2_kernel<<<bs, 256, 0, stream>>>(headsC, q_b1, q_w2, q_b2, v_b1, v_w2, v_b2,
                                        (float*)d_out);
}

// Round 9
// 197.004 us; speedup vs baseline: 1.4518x; 1.2142x over previous
//
#include <hip/hip_runtime.h>
#include <hip/hip_bf16.h>

typedef unsigned int uint_t;
typedef unsigned short ushort_t;
typedef __attribute__((ext_vector_type(8))) short short8;
typedef __attribute__((ext_vector_type(4))) float floatx4;

__device__ __forceinline__ float4 fma4(float4 a, float s, float4 w){
  a.x += s*w.x; a.y += s*w.y; a.z += s*w.z; a.w += s*w.w; return a;
}
__device__ __forceinline__ float4 relu4(float4 a){
  return make_float4(fmaxf(a.x,0.f),fmaxf(a.y,0.f),fmaxf(a.z,0.f),fmaxf(a.w,0.f));
}
__device__ __forceinline__ float comp4(float4 v, int k){
  return k==0? v.x : k==1? v.y : k==2? v.z : v.w;
}
__device__ __forceinline__ unsigned bf16rne(float f){
  unsigned u = __float_as_uint(f);
  return (u + 0x7fffu + ((u>>16)&1u)) >> 16;
}
__device__ __forceinline__ uint_t packbf(float f){
  unsigned hb = bf16rne(f);
  float hf = __uint_as_float(hb<<16);
  unsigned lb = bf16rne(f - hf);
  return (hb<<16) | lb;
}
__device__ __forceinline__ uint4 pack4(float4 v){
  uint4 u; u.x=packbf(v.x); u.y=packbf(v.y); u.z=packbf(v.z); u.w=packbf(v.w); return u;
}
__device__ __forceinline__ float unpk(uint_t u){
  return __uint_as_float(u & 0xffff0000u) + __uint_as_float(u<<16);
}

// Fragment-order offset (elements): off(n,k) = (n>>4)*16*K + (k>>5)*512 + (n&15)*32 + (k&31)

// =============== K1: enc (blocks 0..511, 4/sample) + weight convert (512..1471) ===============
__global__ __launch_bounds__(256) void prep_kernel(
    const float* __restrict__ obs,
    const float* __restrict__ enc_w1, const float* __restrict__ enc_b1,
    const float* __restrict__ enc_w2, const float* __restrict__ enc_b2,
    const float* __restrict__ wl1, const float* __restrict__ wr1,
    const float* __restrict__ wl2,
    const float* __restrict__ q_w1, const float* __restrict__ v_w1,
    ushort_t* __restrict__ wl1Thi, ushort_t* __restrict__ wl1Tlo,
    ushort_t* __restrict__ wr1Thi, ushort_t* __restrict__ wr1Tlo,
    ushort_t* __restrict__ wl2Thi, ushort_t* __restrict__ wl2Tlo,
    ushort_t* __restrict__ qw1Thi, ushort_t* __restrict__ qw1Tlo,
    ushort_t* __restrict__ vw1Thi, ushort_t* __restrict__ vw1Tlo,
    uint_t* __restrict__ xpk,     // fragment order, K=128
    uint_t* __restrict__ xcatpk,  // fragment order, K=1152, M=128
    unsigned* __restrict__ adjw, int* __restrict__ aiw)
{
  const int t = threadIdx.x, bid = blockIdx.x;
  if (bid >= 512){
    __shared__ float sm[32][33];
    const int cw = bid - 512;
    const float* in; ushort_t* ohi; ushort_t* olo; int K, N, tt;
    if (cw < 64)        { in=wl1;  ohi=wl1Thi; olo=wl1Tlo; K=128;  N=512; tt=cw; }
    else if (cw < 128)  { in=wr1;  ohi=wr1Thi; olo=wr1Tlo; K=128;  N=512; tt=cw-64; }
    else if (cw < 384)  { in=wl2;  ohi=wl2Thi; olo=wl2Tlo; K=512;  N=512; tt=cw-128; }
    else if (cw < 672)  { in=q_w1; ohi=qw1Thi; olo=qw1Tlo; K=1152; N=256; tt=cw-384; }
    else                { in=v_w1; ohi=vw1Thi; olo=vw1Tlo; K=1152; N=256; tt=cw-672; }
    const int ktiles = K>>5;
    const int kt = tt % ktiles, nt = tt / ktiles;
    const int r = t>>5, c = t&31;
    #pragma unroll
    for (int i=0;i<4;i++)
      sm[r+i*8][c] = in[(size_t)(kt*32 + r + i*8)*N + nt*32 + c];
    __syncthreads();
    #pragma unroll
    for (int i=0;i<4;i++){
      const int nl = r + i*8;
      const int n  = nt*32 + nl;
      const float f = sm[c][nl];
      const unsigned hb = bf16rne(f);
      const float hf = __uint_as_float(hb<<16);
      const unsigned lb = bf16rne(f - hf);
      const size_t off = (size_t)(n>>4)*(16*K) + (size_t)kt*512 + (size_t)(n&15)*32 + c;
      ohi[off] = (ushort_t)hb;
      olo[off] = (ushort_t)lb;
    }
    return;
  }
  // ---------------- encoder: block (s, g), nodes g*8..g*8+7 ----------------
  __shared__ float s_pos[64];
  __shared__ float s_feats[128];
  __shared__ __align__(16) float s_h[8*132];
  __shared__ int s_ai;
  const int s = bid>>2, g = bid&3;
  const float* ob = obs + s*577;

  if (t==0){
    float a = ob[576];
    a = fminf(fmaxf(a, 0.f), 31.f);
    s_ai = (int)a;
    if (g==0) aiw[s] = (int)a;
  }
  if (t < 128){ const int n=t>>4, f=t&15; s_feats[t] = ob[(g*8+n)*18+2+f]; }
  if (g==0 && t>=128 && t<192){ const int u=t-128; s_pos[u] = ob[(u>>1)*18 + (u&1)]; }
  __syncthreads();

  if (g==0 && t < 32){
    const float px = s_pos[2*t], py = s_pos[2*t+1];
    const float R2 = 0.09f;
    unsigned mm = 0u;
    for (int j=0;j<32;j++){
      const float dx = __fsub_rn(px, s_pos[2*j]), dy = __fsub_rn(py, s_pos[2*j+1]);
      const float d2 = __fadd_rn(__fmul_rn(dx,dx), __fmul_rn(dy,dy));
      if (d2 <= R2 || j==t) mm |= (1u<<j);
    }
    adjw[s*32+t] = mm;
  }

  const int n = t>>5, c0 = (t&31)*4;
  // enc1: h[n][c0..c0+4]
  {
    float4 a = *(const float4*)(enc_b1+c0);
    #pragma unroll
    for (int f=0; f<16; f++)
      a = fma4(a, s_feats[n*16+f], *(const float4*)(enc_w1 + f*128 + c0));
    *(float4*)&s_h[n*132+c0] = relu4(a);
  }
  __syncthreads();
  // enc2 -> packed x + tap
  {
    float4 a = *(const float4*)(enc_b2+c0);
    for (int k=0;k<128;k+=4){
      const float4 hv = *(const float4*)&s_h[n*132+k];
      a = fma4(a, hv.x, *(const float4*)(enc_w2 + (k+0)*128 + c0));
      a = fma4(a, hv.y, *(const float4*)(enc_w2 + (k+1)*128 + c0));
      a = fma4(a, hv.z, *(const float4*)(enc_w2 + (k+2)*128 + c0));
      a = fma4(a, hv.w, *(const float4*)(enc_w2 + (k+3)*128 + c0));
    }
    a = relu4(a);
    const uint4 p = pack4(a);
    const int i = g*8 + n;
    uint_t* xp = xpk + (size_t)(s*2 + (i>>4))*2048 + (c0>>5)*512 + (i&15)*32 + (c0&31);
    *(uint4*)xp = p;
    if (i == s_ai){
      uint_t* xc = xcatpk + (size_t)(s>>4)*18432 + (c0>>5)*512 + (s&15)*32 + (c0&31);
      *(uint4*)xc = p;
    }
  }
}

// =============== K2: fused proj1 + attn1, block = (s,h) ===============
__global__ __launch_bounds__(256) void pa1_kernel(
    const uint_t* __restrict__ xpk,
    const ushort_t* __restrict__ wl1Thi, const ushort_t* __restrict__ wl1Tlo,
    const ushort_t* __restrict__ wr1Thi, const ushort_t* __restrict__ wr1Tlo,
    const float* __restrict__ att, const float* __restrict__ bias,
    const unsigned* __restrict__ adjw, const int* __restrict__ aiw,
    uint_t* __restrict__ x2pk,    // fragment order K=512
    uint_t* __restrict__ xcatpk)  // fragment order K=1152
{
  __shared__ __align__(16) float s_gl[32*132];
  __shared__ __align__(16) float s_gr[32*132];
  __shared__ __align__(16) float s_att[128];
  __shared__ __align__(16) float s_b[128];
  __shared__ float s_lg[32*33];
  __shared__ unsigned s_adj[32];
  const int t = threadIdx.x;
  const int s = blockIdx.x >> 2, h = blockIdx.x & 3;
  const int w = t>>6, lane = t&63, m = lane&15, quad = lane>>4;

  // stage small tensors (consumed after barrier)
  if (t < 128){ s_att[t] = att[h*128 + t]; s_b[t] = bias[h*128 + t]; }
  if (t >= 224) s_adj[t-224] = adjw[s*32 + (t-224)];
  const int ai = aiw[s];

  // ---- MFMA: waves 0,1 -> gl cols (w&1)*64..+64 ; waves 2,3 -> gr ----
  const ushort_t* Bhi = (w<2) ? wl1Thi : wr1Thi;
  const ushort_t* Blo = (w<2) ? wl1Tlo : wr1Tlo;
  const int nbase = h*8 + (w&1)*4;
  const uint_t* a0p = xpk + (size_t)(s*2+0)*2048 + m*32 + quad*8;
  const uint_t* a1p = xpk + (size_t)(s*2+1)*2048 + m*32 + quad*8;
  const ushort_t* bp0 = Bhi + (size_t)(nbase+0)*2048 + m*32 + quad*8;
  const ushort_t* bp1 = Bhi + (size_t)(nbase+1)*2048 + m*32 + quad*8;
  const ushort_t* bp2 = Bhi + (size_t)(nbase+2)*2048 + m*32 + quad*8;
  const ushort_t* bp3 = Bhi + (size_t)(nbase+3)*2048 + m*32 + quad*8;
  const size_t lod = (size_t)(Blo - Bhi);
  floatx4 acc[2][4];
  #pragma unroll
  for (int i=0;i<2;i++)
    #pragma unroll
    for (int j=0;j<4;j++) acc[i][j] = (floatx4){0.f,0.f,0.f,0.f};

  #pragma unroll
  for (int kc=0; kc<4; kc++){
    const uint4 u00 = *(const uint4*)(a0p + kc*512);
    const uint4 u01 = *(const uint4*)(a0p + kc*512 + 4);
    const uint4 u10 = *(const uint4*)(a1p + kc*512);
    const uint4 u11 = *(const uint4*)(a1p + kc*512 + 4);
    short8 ahi0, alo0, ahi1, alo1;
    ahi0[0]=(short)(u00.x>>16); alo0[0]=(short)u00.x;
    ahi0[1]=(short)(u00.y>>16); alo0[1]=(short)u00.y;
    ahi0[2]=(short)(u00.z>>16); alo0[2]=(short)u00.z;
    ahi0[3]=(short)(u00.w>>16); alo0[3]=(short)u00.w;
    ahi0[4]=(short)(u01.x>>16); alo0[4]=(short)u01.x;
    ahi0[5]=(short)(u01.y>>16); alo0[5]=(short)u01.y;
    ahi0[6]=(short)(u01.z>>16); alo0[6]=(short)u01.z;
    ahi0[7]=(short)(u01.w>>16); alo0[7]=(short)u01.w;
    ahi1[0]=(short)(u10.x>>16); alo1[0]=(short)u10.x;
    ahi1[1]=(short)(u10.y>>16); alo1[1]=(short)u10.y;
    ahi1[2]=(short)(u10.z>>16); alo1[2]=(short)u10.z;
    ahi1[3]=(short)(u10.w>>16); alo1[3]=(short)u10.w;
    ahi1[4]=(short)(u11.x>>16); alo1[4]=(short)u11.x;
    ahi1[5]=(short)(u11.y>>16); alo1[5]=(short)u11.y;
    ahi1[6]=(short)(u11.z>>16); alo1[6]=(short)u11.z;
    ahi1[7]=(short)(u11.w>>16); alo1[7]=(short)u11.w;
    const ushort_t* bps[4] = {bp0, bp1, bp2, bp3};
    #pragma unroll
    for (int nt=0; nt<4; nt++){
      const short8 bh = *(const short8*)(bps[nt] + kc*512);
      const short8 bl = *(const short8*)(bps[nt] + kc*512 + lod);
      acc[0][nt] = __builtin_amdgcn_mfma_f32_16x16x32_bf16(ahi0, bh, acc[0][nt], 0,0,0);
      acc[0][nt] = __builtin_amdgcn_mfma_f32_16x16x32_bf16(ahi0, bl, acc[0][nt], 0,0,0);
      acc[0][nt] = __builtin_amdgcn_mfma_f32_16x16x32_bf16(alo0, bh, acc[0][nt], 0,0,0);
      acc[1][nt] = __builtin_amdgcn_mfma_f32_16x16x32_bf16(ahi1, bh, acc[1][nt], 0,0,0);
      acc[1][nt] = __builtin_amdgcn_mfma_f32_16x16x32_bf16(ahi1, bl, acc[1][nt], 0,0,0);
      acc[1][nt] = __builtin_amdgcn_mfma_f32_16x16x32_bf16(alo1, bh, acc[1][nt], 0,0,0);
    }
  }
  // write tiles to LDS (C layout: row=quad*4+r, col=nt*16+m)
  {
    float* dst = (w<2) ? s_gl : s_gr;
    const int colbase = (w&1)*64;
    #pragma unroll
    for (int nt=0; nt<4; nt++){
      const int col = colbase + nt*16 + m;
      #pragma unroll
      for (int r=0;r<4;r++){
        dst[(quad*4+r)*132 + col]      = acc[0][nt][r];
        dst[(16+quad*4+r)*132 + col]   = acc[1][nt][r];
      }
    }
  }
  __syncthreads();

  // ---- logits ----
  {
    const int i = t>>3, jb = t&7;
    float lacc[4] = {0.f,0.f,0.f,0.f};
    for (int c=0;c<128;c+=4){
      const float4 g = *(const float4*)&s_gr[i*132+c];
      const float4 a = *(const float4*)&s_att[c];
      #pragma unroll
      for (int mm=0;mm<4;mm++){
        const float4 gj = *(const float4*)&s_gl[(jb+8*mm)*132 + c];
        float ex = g.x+gj.x; ex = fmaxf(ex, 0.2f*ex);
        float ey = g.y+gj.y; ey = fmaxf(ey, 0.2f*ey);
        float ez = g.z+gj.z; ez = fmaxf(ez, 0.2f*ez);
        float ew = g.w+gj.w; ew = fmaxf(ew, 0.2f*ew);
        lacc[mm] += ex*a.x + ey*a.y + ez*a.z + ew*a.w;
      }
    }
    #pragma unroll
    for (int mm=0;mm<4;mm++) s_lg[i*33 + jb + 8*mm] = lacc[mm];
  }
  __syncthreads();

  // ---- masked softmax ----
  for (int rnd=0; rnd<4; rnd++){
    const int i = rnd*8 + (t>>5), j = t&31;
    const float lg = s_lg[i*33+j];
    const bool ok = (s_adj[i]>>j)&1u;
    float v = ok ? lg : -3.0e38f;
    #pragma unroll
    for (int d_=16; d_; d_>>=1) v = fmaxf(v, __shfl_xor(v, d_, 32));
    const float e = ok ? __expf(lg - v) : 0.f;
    float sum = e;
    #pragma unroll
    for (int d_=16; d_; d_>>=1) sum += __shfl_xor(sum, d_, 32);
    s_lg[i*33+j] = e / sum;
  }
  __syncthreads();

  // ---- aggregate -> packed x2 + tap ----
  {
    const int i = t>>3, c0 = (t&7)*16;
    float4 o0 = make_float4(0.f,0.f,0.f,0.f), o1 = o0, o2 = o0, o3 = o0;
    for (int j=0;j<32;j++){
      const float al = s_lg[i*33+j];
      o0 = fma4(o0, al, *(const float4*)&s_gl[j*132 + c0]);
      o1 = fma4(o1, al, *(const float4*)&s_gl[j*132 + c0 + 4]);
      o2 = fma4(o2, al, *(const float4*)&s_gl[j*132 + c0 + 8]);
      o3 = fma4(o3, al, *(const float4*)&s_gl[j*132 + c0 + 12]);
    }
    const float4 b0 = *(const float4*)&s_b[c0];
    const float4 b1 = *(const float4*)&s_b[c0+4];
    const float4 b2 = *(const float4*)&s_b[c0+8];
    const float4 b3 = *(const float4*)&s_b[c0+12];
    o0 = relu4(make_float4(o0.x+b0.x, o0.y+b0.y, o0.z+b0.z, o0.w+b0.w));
    o1 = relu4(make_float4(o1.x+b1.x, o1.y+b1.y, o1.z+b1.z, o1.w+b1.w));
    o2 = relu4(make_float4(o2.x+b2.x, o2.y+b2.y, o2.z+b2.z, o2.w+b2.w));
    o3 = relu4(make_float4(o3.x+b3.x, o3.y+b3.y, o3.z+b3.z, o3.w+b3.w));
    const uint4 p0 = pack4(o0), p1 = pack4(o1), p2 = pack4(o2), p3 = pack4(o3);
    const int kb = h*128 + c0;
    uint_t* xp = x2pk + (size_t)(s*2 + (i>>4))*8192 + (kb>>5)*512 + (i&15)*32 + (kb&31);
    *(uint4*)&xp[0]  = p0;
    *(uint4*)&xp[4]  = p1;
    *(uint4*)&xp[8]  = p2;
    *(uint4*)&xp[12] = p3;
    if (i == ai){
      const int kk = 128 + kb;
      uint_t* tp = xcatpk + (size_t)(s>>4)*18432 + (kk>>5)*512 + (s&15)*32 + (kk&31);
      *(uint4*)&tp[0]  = p0;
      *(uint4*)&tp[4]  = p1;
      *(uint4*)&tp[8]  = p2;
      *(uint4*)&tp[12] = p3;
    }
  }
}

// =============== K3: fused proj2 + grtap + attn2, block = (s,h) ===============
__global__ __launch_bounds__(256) void pa2_kernel(
    const uint_t* __restrict__ x2pk,
    const ushort_t* __restrict__ wl2Thi, const ushort_t* __restrict__ wl2Tlo,
    const float* __restrict__ wr2f,   // original fp32 [512][512]
    const float* __restrict__ att2, const float* __restrict__ bias2,
    const unsigned* __restrict__ adjw, const int* __restrict__ aiw,
    uint_t* __restrict__ xcatpk)
{
  __shared__ __align__(16) float s_gl[32*132];
  __shared__ __align__(16) float s_xt[512];
  __shared__ __align__(16) float s_p2[2*128];
  __shared__ __align__(16) float s_at[128];
  __shared__ __align__(16) float s_bb[128];
  __shared__ float s_lg[32];
  __shared__ float s_al[32];
  const int t = threadIdx.x;
  const int s = blockIdx.x >> 2, h = blockIdx.x & 3;
  const int w = t>>6, lane = t&63, m = lane&15, quad = lane>>4;
  const int ai = aiw[s];
  const unsigned arow = adjw[s*32+ai];

  // stage x2tap (fp32 from packed xcat region k=128..640) + att/bias
  for (int e=t; e<512; e+=256){
    const int kk = 128 + e;
    s_xt[e] = unpk(xcatpk[(size_t)(s>>4)*18432 + (kk>>5)*512 + (s&15)*32 + (kk&31)]);
  }
  if (t < 128){ s_at[t] = att2[h*128+t]; s_bb[t] = bias2[h*128+t]; }
  __syncthreads();

  // ---- grt slice (fp32 VALU): c = t&127, half = t>>7 ----
  {
    const int c = t&127, half = t>>7;
    const float* wp = wr2f + (size_t)(half*256)*512 + h*128 + c;
    float ga = 0.f;
    #pragma unroll 8
    for (int k=0;k<256;k++) ga += s_xt[half*256 + k] * wp[(size_t)k*512];
    s_p2[half*128 + c] = ga;
  }

  // ---- MFMA gl2 tile: wave w covers ntiles w*2, w*2+1 (cols w*32..+32) ----
  const uint_t* a0p = x2pk + (size_t)(s*2+0)*8192 + m*32 + quad*8;
  const uint_t* a1p = x2pk + (size_t)(s*2+1)*8192 + m*32 + quad*8;
  const ushort_t* bq0 = wl2Thi + (size_t)(h*8 + w*2+0)*8192 + m*32 + quad*8;
  const ushort_t* bq1 = wl2Thi + (size_t)(h*8 + w*2+1)*8192 + m*32 + quad*8;
  const size_t lod = (size_t)(wl2Tlo - wl2Thi);
  floatx4 acc[2][2];
  #pragma unroll
  for (int i=0;i<2;i++){ acc[i][0] = (floatx4){0.f,0.f,0.f,0.f}; acc[i][1] = acc[i][0]; }
  for (int kc=0; kc<16; kc++){
    const uint4 u00 = *(const uint4*)(a0p + kc*512);
    const uint4 u01 = *(const uint4*)(a0p + kc*512 + 4);
    const uint4 u10 = *(const uint4*)(a1p + kc*512);
    const uint4 u11 = *(const uint4*)(a1p + kc*512 + 4);
    short8 ahi0, alo0, ahi1, alo1;
    ahi0[0]=(short)(u00.x>>16); alo0[0]=(short)u00.x;
    ahi0[1]=(short)(u00.y>>16); alo0[1]=(short)u00.y;
    ahi0[2]=(short)(u00.z>>16); alo0[2]=(short)u00.z;
    ahi0[3]=(short)(u00.w>>16); alo0[3]=(short)u00.w;
    ahi0[4]=(short)(u01.x>>16); alo0[4]=(short)u01.x;
    ahi0[5]=(short)(u01.y>>16); alo0[5]=(short)u01.y;
    ahi0[6]=(short)(u01.z>>16); alo0[6]=(short)u01.z;
    ahi0[7]=(short)(u01.w>>16); alo0[7]=(short)u01.w;
    ahi1[0]=(short)(u10.x>>16); alo1[0]=(short)u10.x;
    ahi1[1]=(short)(u10.y>>16); alo1[1]=(short)u10.y;
    ahi1[2]=(short)(u10.z>>16); alo1[2]=(short)u10.z;
    ahi1[3]=(short)(u10.w>>16); alo1[3]=(short)u10.w;
    ahi1[4]=(short)(u11.x>>16); alo1[4]=(short)u11.x;
    ahi1[5]=(short)(u11.y>>16); alo1[5]=(short)u11.y;
    ahi1[6]=(short)(u11.z>>16); alo1[6]=(short)u11.z;
    ahi1[7]=(short)(u11.w>>16); alo1[7]=(short)u11.w;
    {
      const short8 bh = *(const short8*)(bq0 + kc*512);
      const short8 bl = *(const short8*)(bq0 + kc*512 + lod);
      acc[0][0] = __builtin_amdgcn_mfma_f32_16x16x32_bf16(ahi0, bh, acc[0][0], 0,0,0);
      acc[0][0] = __builtin_amdgcn_mfma_f32_16x16x32_bf16(ahi0, bl, acc[0][0], 0,0,0);
      acc[0][0] = __builtin_amdgcn_mfma_f32_16x16x32_bf16(alo0, bh, acc[0][0], 0,0,0);
      acc[1][0] = __builtin_amdgcn_mfma_f32_16x16x32_bf16(ahi1, bh, acc[1][0], 0,0,0);
      acc[1][0] = __builtin_amdgcn_mfma_f32_16x16x32_bf16(ahi1, bl, acc[1][0], 0,0,0);
      acc[1][0] = __builtin_amdgcn_mfma_f32_16x16x32_bf16(alo1, bh, acc[1][0], 0,0,0);
    }
    {
      const short8 bh = *(const short8*)(bq1 + kc*512);
      const short8 bl = *(const short8*)(bq1 + kc*512 + lod);
      acc[0][1] = __builtin_amdgcn_mfma_f32_16x16x32_bf16(ahi0, bh, acc[0][1], 0,0,0);
      acc[0][1] = __builtin_amdgcn_mfma_f32_16x16x32_bf16(ahi0, bl, acc[0][1], 0,0,0);
      acc[0][1] = __builtin_amdgcn_mfma_f32_16x16x32_bf16(alo0, bh, acc[0][1], 0,0,0);
      acc[1][1] = __builtin_amdgcn_mfma_f32_16x16x32_bf16(ahi1, bh, acc[1][1], 0,0,0);
      acc[1][1] = __builtin_amdgcn_mfma_f32_16x16x32_bf16(ahi1, bl, acc[1][1], 0,0,0);
      acc[1][1] = __builtin_amdgcn_mfma_f32_16x16x32_bf16(alo1, bh, acc[1][1], 0,0,0);
    }
  }
  {
    const int colbase = w*32;
    #pragma unroll
    for (int nt=0; nt<2; nt++){
      const int col = colbase + nt*16 + m;
      #pragma unroll
      for (int r=0;r<4;r++){
        s_gl[(quad*4+r)*132 + col]    = acc[0][nt][r];
        s_gl[(16+quad*4+r)*132 + col] = acc[1][nt][r];
      }
    }
  }
  __syncthreads();

  // combine grt halves
  if (t < 128) s_p2[t] = s_p2[t] + s_p2[128+t];
  __syncthreads();

  // ---- attn2 logits (row ai) ----
  {
    const int j = t>>3, p = t&7;
    float sum = 0.f;
    #pragma unroll
    for (int q=0;q<4;q++){
      const int c = p*16 + q*4;
      const float4 g = *(const float4*)&s_gl[j*132 + c];
      const float4 r = *(const float4*)&s_p2[c];
      const float4 a = *(const float4*)&s_at[c];
      float e0 = r.x+g.x; e0 = fmaxf(e0, 0.2f*e0);
      float e1 = r.y+g.y; e1 = fmaxf(e1, 0.2f*e1);
      float e2 = r.z+g.z; e2 = fmaxf(e2, 0.2f*e2);
      float e3 = r.w+g.w; e3 = fmaxf(e3, 0.2f*e3);
      sum += e0*a.x + e1*a.y + e2*a.z + e3*a.w;
    }
    sum += __shfl_xor(sum,1,64);
    sum += __shfl_xor(sum,2,64);
    sum += __shfl_xor(sum,4,64);
    if (p==0) s_lg[j] = sum;
  }
  __syncthreads();
  if (t < 32){
    const float lg = s_lg[t];
    const bool ok = (arow>>t)&1u;
    float v = ok ? lg : -3.0e38f;
    #pragma unroll
    for (int d_=16; d_; d_>>=1) v = fmaxf(v, __shfl_xor(v, d_, 32));
    const float e = ok ? __expf(lg - v) : 0.f;
    float sm = e;
    #pragma unroll
    for (int d_=16; d_; d_>>=1) sm += __shfl_xor(sm, d_, 32);
    s_al[t] = e / sm;
  }
  __syncthreads();
  if (t < 128){
    float acc2 = 0.f;
    #pragma unroll 8
    for (int j=0;j<32;j++) acc2 += s_al[j] * s_gl[j*132 + t];
    const int kk = 640 + h*128 + t;
    xcatpk[(size_t)(s>>4)*18432 + (kk>>5)*512 + (s&15)*32 + (kk&31)]
        = packbf(fmaxf(acc2 + s_bb[t], 0.f));
  }
}

// =============== K4: heads GEMM (fragment-order A and B) ===============
template<int KD>
__global__ __launch_bounds__(256) void mfma_gemm(
    const uint_t* __restrict__ A1, int rbs1,
    const ushort_t* __restrict__ B0hi, const ushort_t* __restrict__ B0lo,
    const ushort_t* __restrict__ B1hi, const ushort_t* __restrict__ B1lo,
    float* __restrict__ C0, float* __restrict__ C1,
    int nct1, int ctsplit)
{
  const int t = threadIdx.x;
  const int w = t>>6, lane = t&63;
  const int m = lane & 15, quad = lane >> 4;
  const int bid = blockIdx.x;
  const int rt = bid / nct1, ct = bid % nct1;
  const ushort_t* Bhi; const ushort_t* Blo; float* C; int cb;
  if (ct < ctsplit){ Bhi = B0hi; Blo = B0lo; C = C0; cb = ct*64; }
  else             { Bhi = B1hi; Blo = B1lo; C = C1; cb = (ct-ctsplit)*64; }
  const uint_t* ap = A1 + (size_t)(rt*4 + w)*rbs1 + m*32 + quad*8;
  const ushort_t* bp0 = Bhi + (size_t)((cb>>4)+0)*(16*KD) + m*32 + quad*8;
  const ushort_t* bp1 = Bhi + (size_t)((cb>>4)+1)*(16*KD) + m*32 + quad*8;
  const ushort_t* bp2 = Bhi + (size_t)((cb>>4)+2)*(16*KD) + m*32 + quad*8;
  const ushort_t* bp3 = Bhi + (size_t)((cb>>4)+3)*(16*KD) + m*32 + quad*8;
  const size_t lod = (size_t)(Blo - Bhi);
  floatx4 acc[4];
  #pragma unroll
  for (int i=0;i<4;i++) acc[i] = (floatx4){0.f,0.f,0.f,0.f};

  for (int kc=0; kc<KD/32; kc++){
    const uint4 ua0 = *(const uint4*)(ap);
    const uint4 ua1 = *(const uint4*)(ap+4);
    ap += 512;
    short8 ahi, alo;
    ahi[0]=(short)(ua0.x>>16); alo[0]=(short)(ua0.x);
    ahi[1]=(short)(ua0.y>>16); alo[1]=(short)(ua0.y);
    ahi[2]=(short)(ua0.z>>16); alo[2]=(short)(ua0.z);
    ahi[3]=(short)(ua0.w>>16); alo[3]=(short)(ua0.w);
    ahi[4]=(short)(ua1.x>>16); alo[4]=(short)(ua1.x);
    ahi[5]=(short)(ua1.y>>16); alo[5]=(short)(ua1.y);
    ahi[6]=(short)(ua1.z>>16); alo[6]=(short)(ua1.z);
    ahi[7]=(short)(ua1.w>>16); alo[7]=(short)(ua1.w);
    {
      const short8 bh = *(const short8*)(bp0);
      const short8 bl = *(const short8*)(bp0 + lod);
      acc[0] = __builtin_amdgcn_mfma_f32_16x16x32_bf16(ahi, bh, acc[0], 0,0,0);
      acc[0] = __builtin_amdgcn_mfma_f32_16x16x32_bf16(ahi, bl, acc[0], 0,0,0);
      acc[0] = __builtin_amdgcn_mfma_f32_16x16x32_bf16(alo, bh, acc[0], 0,0,0);
      bp0 += 512;
    }
    {
      const short8 bh = *(const short8*)(bp1);
      const short8 bl = *(const short8*)(bp1 + lod);
      acc[1] = __builtin_amdgcn_mfma_f32_16x16x32_bf16(ahi, bh, acc[1], 0,0,0);
      acc[1] = __builtin_amdgcn_mfma_f32_16x16x32_bf16(ahi, bl, acc[1], 0,0,0);
      acc[1] = __builtin_amdgcn_mfma_f32_16x16x32_bf16(alo, bh, acc[1], 0,0,0);
      bp1 += 512;
    }
    {
      const short8 bh = *(const short8*)(bp2);
      const short8 bl = *(const short8*)(bp2 + lod);
      acc[2] = __builtin_amdgcn_mfma_f32_16x16x32_bf16(ahi, bh, acc[2], 0,0,0);
      acc[2] = __builtin_amdgcn_mfma_f32_16x16x32_bf16(ahi, bl, acc[2], 0,0,0);
      acc[2] = __builtin_amdgcn_mfma_f32_16x16x32_bf16(alo, bh, acc[2], 0,0,0);
      bp2 += 512;
    }
    {
      const short8 bh = *(const short8*)(bp3);
      const short8 bl = *(const short8*)(bp3 + lod);
      acc[3] = __builtin_amdgcn_mfma_f32_16x16x32_bf16(ahi, bh, acc[3], 0,0,0);
      acc[3] = __builtin_amdgcn_mfma_f32_16x16x32_bf16(ahi, bl, acc[3], 0,0,0);
      acc[3] = __builtin_amdgcn_mfma_f32_16x16x32_bf16(alo, bh, acc[3], 0,0,0);
      bp3 += 512;
    }
  }
  const int crow0 = rt*64 + w*16 + quad*4;
  #pragma unroll
  for (int nt2=0; nt2<4; nt2++){
    const int col = cb + nt2*16 + m;
    #pragma unroll
    for (int r=0;r<4;r++)
      C[(size_t)(crow0 + r)*512 + col] = acc[nt2][r];
  }
}

// =============== K5: heads epilogue + final combine, block per sample ===============
__global__ __launch_bounds__(256) void heads2_kernel(
    const float* __restrict__ Ch,  // [128][512] = [hq|hv] pre-bias
    const float* __restrict__ q_b1, const float* __restrict__ q_w2, const float* __restrict__ q_b2,
    const float* __restrict__ v_b1, const float* __restrict__ v_w2, const float* __restrict__ v_b2,
    float* __restrict__ out)
{
  __shared__ float s_p[4*6];
  const int t = threadIdx.x, s = blockIdx.x;
  const float hq = fmaxf(Ch[(size_t)s*512 + t]       + q_b1[t], 0.f);
  const float hv = fmaxf(Ch[(size_t)s*512 + 256 + t] + v_b1[t], 0.f);
  float p[6];
  #pragma unroll
  for (int o=0;o<5;o++) p[o] = hq * q_w2[t*5+o];
  p[5] = hv * v_w2[t];
  #pragma unroll
  for (int d_=32; d_; d_>>=1){
    #pragma unroll
    for (int o=0;o<6;o++) p[o] += __shfl_xor(p[o], d_, 64);
  }
  const int w = t>>6, lane = t&63;
  if (lane==0){
    #pragma unroll
    for (int o=0;o<6;o++) s_p[w*6+o] = p[o];
  }
  __syncthreads();
  if (t < 6) s_p[t] = s_p[t] + s_p[6+t] + s_p[12+t] + s_p[18+t];
  __syncthreads();
  if (t < 5){
    const float q0 = s_p[0]+q_b2[0], q1 = s_p[1]+q_b2[1], q2 = s_p[2]+q_b2[2],
                q3 = s_p[3]+q_b2[3], q4 = s_p[4]+q_b2[4];
    const float mean = (q0+q1+q2+q3+q4) / 5.0f;
    const float v = s_p[5] + v_b2[0];
    const float qt = (t==0?q0:t==1?q1:t==2?q2:t==3?q3:q4);
    out[s*5+t] = qt - mean + v;
  }
}

extern "C" void kernel_launch(void* const* d_in, const int* in_sizes, int n_in,
                              void* d_out, int out_size, void* d_ws, size_t ws_size,
                              hipStream_t stream) {
  (void)n_in; (void)out_size; (void)ws_size;
  const float* obs    = (const float*)d_in[0];
  const float* enc_w1 = (const float*)d_in[1];
  const float* enc_b1 = (const float*)d_in[2];
  const float* enc_w2 = (const float*)d_in[3];
  const float* enc_b2 = (const float*)d_in[4];
  const float* wl1    = (const float*)d_in[5];
  const float* wr1    = (const float*)d_in[6];
  const float* att1   = (const float*)d_in[7];
  const float* bias1  = (const float*)d_in[8];
  const float* wl2    = (const float*)d_in[9];
  const float* wr2    = (const float*)d_in[10];
  const float* att2   = (const float*)d_in[11];
  const float* bias2  = (const float*)d_in[12];
  const float* q_w1   = (const float*)d_in[13];
  const float* q_b1   = (const float*)d_in[14];
  const float* q_w2   = (const float*)d_in[15];
  const float* q_b2   = (const float*)d_in[16];
  const float* v_w1   = (const float*)d_in[17];
  const float* v_b1   = (const float*)d_in[18];
  const float* v_w2   = (const float*)d_in[19];
  const float* v_b2   = (const float*)d_in[20];

  // workspace layout (bytes)
  char* ws = (char*)d_ws;
  uint_t*   x_pk    = (uint_t*)  (ws + 0);           // 2,097,152
  uint_t*   xcat_pk = (uint_t*)  (ws + 2097152);     //   589,824
  unsigned* adjw    = (unsigned*)(ws + 2686976);     //    16,384
  int*      aiw     = (int*)     (ws + 2703360);     //       512
  uint_t*   x2_pk   = (uint_t*)  (ws + 2703872);     // 8,388,608
  ushort_t* wl1Thi  = (ushort_t*)(ws + 11092480);    //   131,072 each
  ushort_t* wl1Tlo  = (ushort_t*)(ws + 11223552);
  ushort_t* wr1Thi  = (ushort_t*)(ws + 11354624);
  ushort_t* wr1Tlo  = (ushort_t*)(ws + 11485696);
  ushort_t* wl2Thi  = (ushort_t*)(ws + 11616768);    //   524,288 each
  ushort_t* wl2Tlo  = (ushort_t*)(ws + 12141056);
  ushort_t* qw1Thi  = (ushort_t*)(ws + 12665344);    //   589,824 each
  ushort_t* qw1Tlo  = (ushort_t*)(ws + 13255168);
  ushort_t* vw1Thi  = (ushort_t*)(ws + 13844992);
  ushort_t* vw1Tlo  = (ushort_t*)(ws + 14434816);
  float*    headsC  = (float*)   (ws + 15024640);    //   262,144
  // end 15,286,784

  const int bs = in_sizes[0] / 577;   // 128

  // enc (512 blocks, 4/sample) + weight converts (960 blocks)
  prep_kernel<<<512 + 960, 256, 0, stream>>>(obs, enc_w1, enc_b1, enc_w2, enc_b2,
      wl1, wr1, wl2, q_w1, v_w1,
      wl1Thi, wl1Tlo, wr1Thi, wr1Tlo, wl2Thi, wl2Tlo,
      qw1Thi, qw1Tlo, vw1Thi, vw1Tlo,
      x_pk, xcat_pk, adjw, aiw);

  // fused proj1 + attn1
  pa1_kernel<<<bs*4, 256, 0, stream>>>(x_pk, wl1Thi, wl1Tlo, wr1Thi, wr1Tlo,
                                       att1, bias1, adjw, aiw, x2_pk, xcat_pk);

  // fused proj2 + grtap + attn2
  pa2_kernel<<<bs*4, 256, 0, stream>>>(x2_pk, wl2Thi, wl2Tlo, wr2,
                                       att2, bias2, adjw, aiw, xcat_pk);

  // heads GEMM: [hq|hv] = xcat @ [q_w1|v_w1]  (M=128, K=1152, N=256+256)
  mfma_gemm<1152><<<16, 256, 0, stream>>>(xcat_pk, 18432,
      qw1Thi, qw1Tlo, vw1Thi, vw1Tlo, headsC, headsC + 256, 8, 4);

  heads2_kernel<<<bs, 256, 0, stream>>>(headsC, q_b1, q_w2, q_b2, v_b1, v_w2, v_b2,
                                        (float*)d_out);
}

// Round 10
// 191.830 us; speedup vs baseline: 1.4909x; 1.0270x over previous
//
#include <hip/hip_runtime.h>
#include <hip/hip_bf16.h>

typedef unsigned int uint_t;
typedef unsigned short ushort_t;
typedef __attribute__((ext_vector_type(8))) short short8;
typedef __attribute__((ext_vector_type(4))) float floatx4;

__device__ __forceinline__ float4 fma4(float4 a, float s, float4 w){
  a.x += s*w.x; a.y += s*w.y; a.z += s*w.z; a.w += s*w.w; return a;
}
__device__ __forceinline__ float4 relu4(float4 a){
  return make_float4(fmaxf(a.x,0.f),fmaxf(a.y,0.f),fmaxf(a.z,0.f),fmaxf(a.w,0.f));
}
__device__ __forceinline__ unsigned bf16rne(float f){
  unsigned u = __float_as_uint(f);
  return (u + 0x7fffu + ((u>>16)&1u)) >> 16;
}
__device__ __forceinline__ uint_t packbf(float f){
  unsigned hb = bf16rne(f);
  float hf = __uint_as_float(hb<<16);
  unsigned lb = bf16rne(f - hf);
  return (hb<<16) | lb;
}
__device__ __forceinline__ uint4 pack4(float4 v){
  uint4 u; u.x=packbf(v.x); u.y=packbf(v.y); u.z=packbf(v.z); u.w=packbf(v.w); return u;
}
__device__ __forceinline__ float unpk(uint_t u){
  return __uint_as_float(u & 0xffff0000u) + __uint_as_float(u<<16);
}
#define UNPACK8(u0,u1,hi,lo) \
  hi[0]=(short)(u0.x>>16); lo[0]=(short)u0.x; \
  hi[1]=(short)(u0.y>>16); lo[1]=(short)u0.y; \
  hi[2]=(short)(u0.z>>16); lo[2]=(short)u0.z; \
  hi[3]=(short)(u0.w>>16); lo[3]=(short)u0.w; \
  hi[4]=(short)(u1.x>>16); lo[4]=(short)u1.x; \
  hi[5]=(short)(u1.y>>16); lo[5]=(short)u1.y; \
  hi[6]=(short)(u1.z>>16); lo[6]=(short)u1.z; \
  hi[7]=(short)(u1.w>>16); lo[7]=(short)u1.w;

// Fragment-order offset: off(n,k) = (n>>4)*16*K + (k>>5)*512 + (n&15)*32 + (k&31)

// =============== K1: enc (blocks 0..511) + weight convert (512..1471) ===============
__global__ __launch_bounds__(256) void prep_kernel(
    const float* __restrict__ obs,
    const float* __restrict__ enc_w1, const float* __restrict__ enc_b1,
    const float* __restrict__ enc_w2, const float* __restrict__ enc_b2,
    const float* __restrict__ wl1, const float* __restrict__ wr1,
    const float* __restrict__ wl2,
    const float* __restrict__ q_w1, const float* __restrict__ v_w1,
    ushort_t* __restrict__ wl1Thi, ushort_t* __restrict__ wl1Tlo,
    ushort_t* __restrict__ wr1Thi, ushort_t* __restrict__ wr1Tlo,
    ushort_t* __restrict__ wl2Thi, ushort_t* __restrict__ wl2Tlo,
    ushort_t* __restrict__ qw1Thi, ushort_t* __restrict__ qw1Tlo,
    ushort_t* __restrict__ vw1Thi, ushort_t* __restrict__ vw1Tlo,
    uint_t* __restrict__ xpk, uint_t* __restrict__ xcatpk,
    unsigned* __restrict__ adjw, int* __restrict__ aiw)
{
  const int t = threadIdx.x, bid = blockIdx.x;
  if (bid >= 512){
    __shared__ float sm[32][33];
    const int cw = bid - 512;
    const float* in; ushort_t* ohi; ushort_t* olo; int K, N, tt;
    if (cw < 64)        { in=wl1;  ohi=wl1Thi; olo=wl1Tlo; K=128;  N=512; tt=cw; }
    else if (cw < 128)  { in=wr1;  ohi=wr1Thi; olo=wr1Tlo; K=128;  N=512; tt=cw-64; }
    else if (cw < 384)  { in=wl2;  ohi=wl2Thi; olo=wl2Tlo; K=512;  N=512; tt=cw-128; }
    else if (cw < 672)  { in=q_w1; ohi=qw1Thi; olo=qw1Tlo; K=1152; N=256; tt=cw-384; }
    else                { in=v_w1; ohi=vw1Thi; olo=vw1Tlo; K=1152; N=256; tt=cw-672; }
    const int ktiles = K>>5;
    const int kt = tt % ktiles, nt = tt / ktiles;
    const int r = t>>5, c = t&31;
    #pragma unroll
    for (int i=0;i<4;i++)
      sm[r+i*8][c] = in[(size_t)(kt*32 + r + i*8)*N + nt*32 + c];
    __syncthreads();
    #pragma unroll
    for (int i=0;i<4;i++){
      const int nl = r + i*8;
      const int n  = nt*32 + nl;
      const float f = sm[c][nl];
      const unsigned hb = bf16rne(f);
      const float hf = __uint_as_float(hb<<16);
      const unsigned lb = bf16rne(f - hf);
      const size_t off = (size_t)(n>>4)*(16*K) + (size_t)kt*512 + (size_t)(n&15)*32 + c;
      ohi[off] = (ushort_t)hb;
      olo[off] = (ushort_t)lb;
    }
    return;
  }
  __shared__ float s_pos[64];
  __shared__ float s_feats[128];
  __shared__ __align__(16) float s_h[8*132];
  __shared__ int s_ai;
  const int s = bid>>2, g = bid&3;
  const float* ob = obs + s*577;

  if (t==0){
    float a = ob[576];
    a = fminf(fmaxf(a, 0.f), 31.f);
    s_ai = (int)a;
    if (g==0) aiw[s] = (int)a;
  }
  if (t < 128){ const int n=t>>4, f=t&15; s_feats[t] = ob[(g*8+n)*18+2+f]; }
  if (g==0 && t>=128 && t<192){ const int u=t-128; s_pos[u] = ob[(u>>1)*18 + (u&1)]; }
  __syncthreads();

  if (g==0 && t < 32){
    const float px = s_pos[2*t], py = s_pos[2*t+1];
    const float R2 = 0.09f;
    unsigned mm = 0u;
    for (int j=0;j<32;j++){
      const float dx = __fsub_rn(px, s_pos[2*j]), dy = __fsub_rn(py, s_pos[2*j+1]);
      const float d2 = __fadd_rn(__fmul_rn(dx,dx), __fmul_rn(dy,dy));
      if (d2 <= R2 || j==t) mm |= (1u<<j);
    }
    adjw[s*32+t] = mm;
  }

  const int n = t>>5, c0 = (t&31)*4;
  {
    float4 a = *(const float4*)(enc_b1+c0);
    #pragma unroll
    for (int f=0; f<16; f++)
      a = fma4(a, s_feats[n*16+f], *(const float4*)(enc_w1 + f*128 + c0));
    *(float4*)&s_h[n*132+c0] = relu4(a);
  }
  __syncthreads();
  {
    float4 a = *(const float4*)(enc_b2+c0);
    for (int k=0;k<128;k+=4){
      const float4 hv = *(const float4*)&s_h[n*132+k];
      a = fma4(a, hv.x, *(const float4*)(enc_w2 + (k+0)*128 + c0));
      a = fma4(a, hv.y, *(const float4*)(enc_w2 + (k+1)*128 + c0));
      a = fma4(a, hv.z, *(const float4*)(enc_w2 + (k+2)*128 + c0));
      a = fma4(a, hv.w, *(const float4*)(enc_w2 + (k+3)*128 + c0));
    }
    a = relu4(a);
    const uint4 p = pack4(a);
    const int i = g*8 + n;
    uint_t* xp = xpk + (size_t)(s*2 + (i>>4))*2048 + (c0>>5)*512 + (i&15)*32 + (c0&31);
    *(uint4*)xp = p;
    if (i == s_ai){
      uint_t* xc = xcatpk + (size_t)(s>>4)*18432 + (c0>>5)*512 + (s&15)*32 + (c0&31);
      *(uint4*)xc = p;
    }
  }
}

// =============== K2: fused proj1 + attn1, block = (s,h), 512 threads, K-split waves ===============
__global__ __launch_bounds__(512) void pa1_kernel(
    const uint_t* __restrict__ xpk,
    const ushort_t* __restrict__ wl1Thi, const ushort_t* __restrict__ wl1Tlo,
    const ushort_t* __restrict__ wr1Thi, const ushort_t* __restrict__ wr1Tlo,
    const float* __restrict__ att, const float* __restrict__ bias,
    const unsigned* __restrict__ adjw, const int* __restrict__ aiw,
    uint_t* __restrict__ x2pk, uint_t* __restrict__ xcatpk)
{
  __shared__ __align__(16) float s_gl[32*132];
  __shared__ __align__(16) float s_glB[32*132];
  __shared__ __align__(16) float s_gr[32*132];
  __shared__ __align__(16) float s_grB[32*132];
  __shared__ __align__(16) float s_att[128];
  __shared__ __align__(16) float s_b[128];
  __shared__ float s_lg[32*33];
  __shared__ unsigned s_adj[32];
  const int t = threadIdx.x;
  const int s = blockIdx.x >> 2, h = blockIdx.x & 3;
  const int w = t>>6, lane = t&63, m = lane&15, quad = lane>>4;
  const int ww = w&3, khalf = w>>2;

  if (t < 128){ s_att[t] = att[h*128 + t]; s_b[t] = bias[h*128 + t]; }
  if (t >= 224 && t < 256) s_adj[t-224] = adjw[s*32 + (t-224)];
  const int ai = aiw[s];

  // ---- MFMA: ww<2 -> gl cols (ww&1)*64..+64 ; ww>=2 -> gr ; khalf splits kc {0,1}/{2,3} ----
  const ushort_t* Bhi = (ww<2) ? wl1Thi : wr1Thi;
  const ushort_t* Blo = (ww<2) ? wl1Tlo : wr1Tlo;
  const int nbase = h*8 + (ww&1)*4;
  const int kcb = khalf*2;
  const uint_t* a0p = xpk + (size_t)(s*2+0)*2048 + m*32 + quad*8 + kcb*512;
  const uint_t* a1p = xpk + (size_t)(s*2+1)*2048 + m*32 + quad*8 + kcb*512;
  const ushort_t* bp0 = Bhi + (size_t)(nbase+0)*2048 + m*32 + quad*8 + kcb*512;
  const ushort_t* bp1 = Bhi + (size_t)(nbase+1)*2048 + m*32 + quad*8 + kcb*512;
  const ushort_t* bp2 = Bhi + (size_t)(nbase+2)*2048 + m*32 + quad*8 + kcb*512;
  const ushort_t* bp3 = Bhi + (size_t)(nbase+3)*2048 + m*32 + quad*8 + kcb*512;
  const size_t lod = (size_t)(Blo - Bhi);
  floatx4 acc[2][4];
  #pragma unroll
  for (int i=0;i<2;i++)
    #pragma unroll
    for (int j=0;j<4;j++) acc[i][j] = (floatx4){0.f,0.f,0.f,0.f};

  #pragma unroll
  for (int kc=0; kc<2; kc++){
    const uint4 u00 = *(const uint4*)(a0p + kc*512);
    const uint4 u01 = *(const uint4*)(a0p + kc*512 + 4);
    const uint4 u10 = *(const uint4*)(a1p + kc*512);
    const uint4 u11 = *(const uint4*)(a1p + kc*512 + 4);
    short8 ahi0, alo0, ahi1, alo1;
    UNPACK8(u00,u01,ahi0,alo0)
    UNPACK8(u10,u11,ahi1,alo1)
    const ushort_t* bps[4] = {bp0, bp1, bp2, bp3};
    #pragma unroll
    for (int nt=0; nt<4; nt++){
      const short8 bh = *(const short8*)(bps[nt] + kc*512);
      const short8 bl = *(const short8*)(bps[nt] + kc*512 + lod);
      acc[0][nt] = __builtin_amdgcn_mfma_f32_16x16x32_bf16(ahi0, bh, acc[0][nt], 0,0,0);
      acc[0][nt] = __builtin_amdgcn_mfma_f32_16x16x32_bf16(ahi0, bl, acc[0][nt], 0,0,0);
      acc[0][nt] = __builtin_amdgcn_mfma_f32_16x16x32_bf16(alo0, bh, acc[0][nt], 0,0,0);
      acc[1][nt] = __builtin_amdgcn_mfma_f32_16x16x32_bf16(ahi1, bh, acc[1][nt], 0,0,0);
      acc[1][nt] = __builtin_amdgcn_mfma_f32_16x16x32_bf16(ahi1, bl, acc[1][nt], 0,0,0);
      acc[1][nt] = __builtin_amdgcn_mfma_f32_16x16x32_bf16(alo1, bh, acc[1][nt], 0,0,0);
    }
  }
  {
    float* dst = (ww<2) ? (khalf ? s_glB : s_gl) : (khalf ? s_grB : s_gr);
    const int colbase = (ww&1)*64;
    #pragma unroll
    for (int nt=0; nt<4; nt++){
      const int col = colbase + nt*16 + m;
      #pragma unroll
      for (int r=0;r<4;r++){
        dst[(quad*4+r)*132 + col]      = acc[0][nt][r];
        dst[(16+quad*4+r)*132 + col]   = acc[1][nt][r];
      }
    }
  }
  __syncthreads();
  for (int e=t; e<32*132; e+=512){
    s_gl[e] += s_glB[e];
    s_gr[e] += s_grB[e];
  }
  __syncthreads();

  // ---- logits (512 threads: i=t>>4, jb=t&15, mm<2) ----
  {
    const int i = t>>4, jb = t&15;
    float lacc[2] = {0.f,0.f};
    for (int c=0;c<128;c+=4){
      const float4 g = *(const float4*)&s_gr[i*132+c];
      const float4 a = *(const float4*)&s_att[c];
      #pragma unroll
      for (int mm=0;mm<2;mm++){
        const float4 gj = *(const float4*)&s_gl[(jb+16*mm)*132 + c];
        float ex = g.x+gj.x; ex = fmaxf(ex, 0.2f*ex);
        float ey = g.y+gj.y; ey = fmaxf(ey, 0.2f*ey);
        float ez = g.z+gj.z; ez = fmaxf(ez, 0.2f*ez);
        float ew = g.w+gj.w; ew = fmaxf(ew, 0.2f*ew);
        lacc[mm] += ex*a.x + ey*a.y + ez*a.z + ew*a.w;
      }
    }
    s_lg[i*33 + jb]      = lacc[0];
    s_lg[i*33 + jb + 16] = lacc[1];
  }
  __syncthreads();

  // ---- masked softmax (2 rounds of 16 rows) ----
  #pragma unroll
  for (int rnd=0; rnd<2; rnd++){
    const int i = rnd*16 + (t>>5), j = t&31;
    const float lg = s_lg[i*33+j];
    const bool ok = (s_adj[i]>>j)&1u;
    float v = ok ? lg : -3.0e38f;
    #pragma unroll
    for (int d_=16; d_; d_>>=1) v = fmaxf(v, __shfl_xor(v, d_, 32));
    const float e = ok ? __expf(lg - v) : 0.f;
    float sum = e;
    #pragma unroll
    for (int d_=16; d_; d_>>=1) sum += __shfl_xor(sum, d_, 32);
    s_lg[i*33+j] = e / sum;
  }
  __syncthreads();

  // ---- aggregate (i=t>>4, 8 cols each) -> packed x2 + tap ----
  {
    const int i = t>>4, c0 = (t&15)*8;
    float4 o0 = make_float4(0.f,0.f,0.f,0.f), o1 = o0;
    for (int j=0;j<32;j++){
      const float al = s_lg[i*33+j];
      o0 = fma4(o0, al, *(const float4*)&s_gl[j*132 + c0]);
      o1 = fma4(o1, al, *(const float4*)&s_gl[j*132 + c0 + 4]);
    }
    const float4 b0 = *(const float4*)&s_b[c0];
    const float4 b1 = *(const float4*)&s_b[c0+4];
    o0 = relu4(make_float4(o0.x+b0.x, o0.y+b0.y, o0.z+b0.z, o0.w+b0.w));
    o1 = relu4(make_float4(o1.x+b1.x, o1.y+b1.y, o1.z+b1.z, o1.w+b1.w));
    const uint4 p0 = pack4(o0), p1 = pack4(o1);
    const int kb = h*128 + c0;
    uint_t* xp = x2pk + (size_t)(s*2 + (i>>4))*8192 + (kb>>5)*512 + (i&15)*32 + (kb&31);
    *(uint4*)&xp[0] = p0;
    *(uint4*)&xp[4] = p1;
    if (i == ai){
      const int kk = 128 + kb;
      uint_t* tp = xcatpk + (size_t)(s>>4)*18432 + (kk>>5)*512 + (s&15)*32 + (kk&31);
      *(uint4*)&tp[0] = p0;
      *(uint4*)&tp[4] = p1;
    }
  }
}

// =============== K3: fused proj2 + grtap + attn2, block = (s,h), 512 threads ===============
__global__ __launch_bounds__(512) void pa2_kernel(
    const uint_t* __restrict__ x2pk,
    const ushort_t* __restrict__ wl2Thi, const ushort_t* __restrict__ wl2Tlo,
    const float* __restrict__ wr2f,
    const float* __restrict__ att2, const float* __restrict__ bias2,
    const unsigned* __restrict__ adjw, const int* __restrict__ aiw,
    uint_t* __restrict__ xcatpk)
{
  __shared__ __align__(16) float s_gl[32*132];
  __shared__ __align__(16) float s_glB[32*132];
  __shared__ __align__(16) float s_xt[512];
  __shared__ __align__(16) float s_p2[4*128];
  __shared__ __align__(16) float s_at[128];
  __shared__ __align__(16) float s_bb[128];
  __shared__ float s_lg[32];
  __shared__ float s_al[32];
  const int t = threadIdx.x;
  const int s = blockIdx.x >> 2, h = blockIdx.x & 3;
  const int w = t>>6, lane = t&63, m = lane&15, quad = lane>>4;
  const int ww = w&3, khalf = w>>2;
  const int ai = aiw[s];
  const unsigned arow = adjw[s*32+ai];

  // stage x2tap (fp32 from packed xcat k=128..640) + att/bias
  {
    const int kk = 128 + t;
    s_xt[t] = unpk(xcatpk[(size_t)(s>>4)*18432 + (kk>>5)*512 + (s&15)*32 + (kk&31)]);
  }
  if (t < 128){ s_at[t] = att2[h*128+t]; s_bb[t] = bias2[h*128+t]; }
  __syncthreads();

  // ---- grt partial (4-way K split): c = t&127, q4 = t>>7 ----
  {
    const int c = t&127, q4 = t>>7;
    const float* wp = wr2f + (size_t)(q4*128)*512 + h*128 + c;
    float ga = 0.f;
    #pragma unroll 8
    for (int k=0;k<128;k++) ga += s_xt[q4*128 + k] * wp[(size_t)k*512];
    s_p2[q4*128 + c] = ga;
  }

  // ---- MFMA gl2: ww covers ntiles ww*2,ww*2+1 (cols ww*32..+32); khalf splits kc 0-7 / 8-15 ----
  const int kcb = khalf*8;
  const uint_t* a0p = x2pk + (size_t)(s*2+0)*8192 + m*32 + quad*8 + kcb*512;
  const uint_t* a1p = x2pk + (size_t)(s*2+1)*8192 + m*32 + quad*8 + kcb*512;
  const ushort_t* bq0 = wl2Thi + (size_t)(h*8 + ww*2+0)*8192 + m*32 + quad*8 + kcb*512;
  const ushort_t* bq1 = wl2Thi + (size_t)(h*8 + ww*2+1)*8192 + m*32 + quad*8 + kcb*512;
  const size_t lod = (size_t)(wl2Tlo - wl2Thi);
  floatx4 acc[2][2];
  #pragma unroll
  for (int i=0;i<2;i++){ acc[i][0] = (floatx4){0.f,0.f,0.f,0.f}; acc[i][1] = acc[i][0]; }
  #pragma unroll 4
  for (int kc=0; kc<8; kc++){
    const uint4 u00 = *(const uint4*)(a0p + kc*512);
    const uint4 u01 = *(const uint4*)(a0p + kc*512 + 4);
    const uint4 u10 = *(const uint4*)(a1p + kc*512);
    const uint4 u11 = *(const uint4*)(a1p + kc*512 + 4);
    short8 ahi0, alo0, ahi1, alo1;
    UNPACK8(u00,u01,ahi0,alo0)
    UNPACK8(u10,u11,ahi1,alo1)
    {
      const short8 bh = *(const short8*)(bq0 + kc*512);
      const short8 bl = *(const short8*)(bq0 + kc*512 + lod);
      acc[0][0] = __builtin_amdgcn_mfma_f32_16x16x32_bf16(ahi0, bh, acc[0][0], 0,0,0);
      acc[0][0] = __builtin_amdgcn_mfma_f32_16x16x32_bf16(ahi0, bl, acc[0][0], 0,0,0);
      acc[0][0] = __builtin_amdgcn_mfma_f32_16x16x32_bf16(alo0, bh, acc[0][0], 0,0,0);
      acc[1][0] = __builtin_amdgcn_mfma_f32_16x16x32_bf16(ahi1, bh, acc[1][0], 0,0,0);
      acc[1][0] = __builtin_amdgcn_mfma_f32_16x16x32_bf16(ahi1, bl, acc[1][0], 0,0,0);
      acc[1][0] = __builtin_amdgcn_mfma_f32_16x16x32_bf16(alo1, bh, acc[1][0], 0,0,0);
    }
    {
      const short8 bh = *(const short8*)(bq1 + kc*512);
      const short8 bl = *(const short8*)(bq1 + kc*512 + lod);
      acc[0][1] = __builtin_amdgcn_mfma_f32_16x16x32_bf16(ahi0, bh, acc[0][1], 0,0,0);
      acc[0][1] = __builtin_amdgcn_mfma_f32_16x16x32_bf16(ahi0, bl, acc[0][1], 0,0,0);
      acc[0][1] = __builtin_amdgcn_mfma_f32_16x16x32_bf16(alo0, bh, acc[0][1], 0,0,0);
      acc[1][1] = __builtin_amdgcn_mfma_f32_16x16x32_bf16(ahi1, bh, acc[1][1], 0,0,0);
      acc[1][1] = __builtin_amdgcn_mfma_f32_16x16x32_bf16(ahi1, bl, acc[1][1], 0,0,0);
      acc[1][1] = __builtin_amdgcn_mfma_f32_16x16x32_bf16(alo1, bh, acc[1][1], 0,0,0);
    }
  }
  {
    float* dst = khalf ? s_glB : s_gl;
    const int colbase = ww*32;
    #pragma unroll
    for (int nt=0; nt<2; nt++){
      const int col = colbase + nt*16 + m;
      #pragma unroll
      for (int r=0;r<4;r++){
        dst[(quad*4+r)*132 + col]    = acc[0][nt][r];
        dst[(16+quad*4+r)*132 + col] = acc[1][nt][r];
      }
    }
  }
  __syncthreads();
  for (int e=t; e<32*132; e+=512) s_gl[e] += s_glB[e];
  if (t < 128) s_p2[t] = s_p2[t] + s_p2[128+t] + s_p2[256+t] + s_p2[384+t];
  __syncthreads();

  // ---- attn2 logits (row ai), t<256 ----
  if (t < 256){
    const int j = t>>3, p = t&7;
    float sum = 0.f;
    #pragma unroll
    for (int q=0;q<4;q++){
      const int c = p*16 + q*4;
      const float4 g = *(const float4*)&s_gl[j*132 + c];
      const float4 r = *(const float4*)&s_p2[c];
      const float4 a = *(const float4*)&s_at[c];
      float e0 = r.x+g.x; e0 = fmaxf(e0, 0.2f*e0);
      float e1 = r.y+g.y; e1 = fmaxf(e1, 0.2f*e1);
      float e2 = r.z+g.z; e2 = fmaxf(e2, 0.2f*e2);
      float e3 = r.w+g.w; e3 = fmaxf(e3, 0.2f*e3);
      sum += e0*a.x + e1*a.y + e2*a.z + e3*a.w;
    }
    sum += __shfl_xor(sum,1,64);
    sum += __shfl_xor(sum,2,64);
    sum += __shfl_xor(sum,4,64);
    if (p==0) s_lg[j] = sum;
  }
  __syncthreads();
  if (t < 32){
    const float lg = s_lg[t];
    const bool ok = (arow>>t)&1u;
    float v = ok ? lg : -3.0e38f;
    #pragma unroll
    for (int d_=16; d_; d_>>=1) v = fmaxf(v, __shfl_xor(v, d_, 32));
    const float e = ok ? __expf(lg - v) : 0.f;
    float sm = e;
    #pragma unroll
    for (int d_=16; d_; d_>>=1) sm += __shfl_xor(sm, d_, 32);
    s_al[t] = e / sm;
  }
  __syncthreads();
  if (t < 128){
    float acc2 = 0.f;
    #pragma unroll 8
    for (int j=0;j<32;j++) acc2 += s_al[j] * s_gl[j*132 + t];
    const int kk = 640 + h*128 + t;
    xcatpk[(size_t)(s>>4)*18432 + (kk>>5)*512 + (s&15)*32 + (kk&31)]
        = packbf(fmaxf(acc2 + s_bb[t], 0.f));
  }
}

// =============== K4: heads GEMM (fragment-order A and B) ===============
template<int KD>
__global__ __launch_bounds__(256) void mfma_gemm(
    const uint_t* __restrict__ A1, int rbs1,
    const ushort_t* __restrict__ B0hi, const ushort_t* __restrict__ B0lo,
    const ushort_t* __restrict__ B1hi, const ushort_t* __restrict__ B1lo,
    float* __restrict__ C0, float* __restrict__ C1,
    int nct1, int ctsplit)
{
  const int t = threadIdx.x;
  const int w = t>>6, lane = t&63;
  const int m = lane & 15, quad = lane >> 4;
  const int bid = blockIdx.x;
  const int rt = bid / nct1, ct = bid % nct1;
  const ushort_t* Bhi; const ushort_t* Blo; float* C; int cb;
  if (ct < ctsplit){ Bhi = B0hi; Blo = B0lo; C = C0; cb = ct*64; }
  else             { Bhi = B1hi; Blo = B1lo; C = C1; cb = (ct-ctsplit)*64; }
  const uint_t* ap = A1 + (size_t)(rt*4 + w)*rbs1 + m*32 + quad*8;
  const ushort_t* bp0 = Bhi + (size_t)((cb>>4)+0)*(16*KD) + m*32 + quad*8;
  const ushort_t* bp1 = Bhi + (size_t)((cb>>4)+1)*(16*KD) + m*32 + quad*8;
  const ushort_t* bp2 = Bhi + (size_t)((cb>>4)+2)*(16*KD) + m*32 + quad*8;
  const ushort_t* bp3 = Bhi + (size_t)((cb>>4)+3)*(16*KD) + m*32 + quad*8;
  const size_t lod = (size_t)(Blo - Bhi);
  floatx4 acc[4];
  #pragma unroll
  for (int i=0;i<4;i++) acc[i] = (floatx4){0.f,0.f,0.f,0.f};

  for (int kc=0; kc<KD/32; kc++){
    const uint4 ua0 = *(const uint4*)(ap);
    const uint4 ua1 = *(const uint4*)(ap+4);
    ap += 512;
    short8 ahi, alo;
    UNPACK8(ua0,ua1,ahi,alo)
    {
      const short8 bh = *(const short8*)(bp0);
      const short8 bl = *(const short8*)(bp0 + lod);
      acc[0] = __builtin_amdgcn_mfma_f32_16x16x32_bf16(ahi, bh, acc[0], 0,0,0);
      acc[0] = __builtin_amdgcn_mfma_f32_16x16x32_bf16(ahi, bl, acc[0], 0,0,0);
      acc[0] = __builtin_amdgcn_mfma_f32_16x16x32_bf16(alo, bh, acc[0], 0,0,0);
      bp0 += 512;
    }
    {
      const short8 bh = *(const short8*)(bp1);
      const short8 bl = *(const short8*)(bp1 + lod);
      acc[1] = __builtin_amdgcn_mfma_f32_16x16x32_bf16(ahi, bh, acc[1], 0,0,0);
      acc[1] = __builtin_amdgcn_mfma_f32_16x16x32_bf16(ahi, bl, acc[1], 0,0,0);
      acc[1] = __builtin_amdgcn_mfma_f32_16x16x32_bf16(alo, bh, acc[1], 0,0,0);
      bp1 += 512;
    }
    {
      const short8 bh = *(const short8*)(bp2);
      const short8 bl = *(const short8*)(bp2 + lod);
      acc[2] = __builtin_amdgcn_mfma_f32_16x16x32_bf16(ahi, bh, acc[2], 0,0,0);
      acc[2] = __builtin_amdgcn_mfma_f32_16x16x32_bf16(ahi, bl, acc[2], 0,0,0);
      acc[2] = __builtin_amdgcn_mfma_f32_16x16x32_bf16(alo, bh, acc[2], 0,0,0);
      bp2 += 512;
    }
    {
      const short8 bh = *(const short8*)(bp3);
      const short8 bl = *(const short8*)(bp3 + lod);
      acc[3] = __builtin_amdgcn_mfma_f32_16x16x32_bf16(ahi, bh, acc[3], 0,0,0);
      acc[3] = __builtin_amdgcn_mfma_f32_16x16x32_bf16(ahi, bl, acc[3], 0,0,0);
      acc[3] = __builtin_amdgcn_mfma_f32_16x16x32_bf16(alo, bh, acc[3], 0,0,0);
      bp3 += 512;
    }
  }
  const int crow0 = rt*64 + w*16 + quad*4;
  #pragma unroll
  for (int nt2=0; nt2<4; nt2++){
    const int col = cb + nt2*16 + m;
    #pragma unroll
    for (int r=0;r<4;r++)
      C[(size_t)(crow0 + r)*512 + col] = acc[nt2][r];
  }
}

// =============== K5: heads epilogue + final combine ===============
__global__ __launch_bounds__(256) void heads2_kernel(
    const float* __restrict__ Ch,
    const float* __restrict__ q_b1, const float* __restrict__ q_w2, const float* __restrict__ q_b2,
    const float* __restrict__ v_b1, const float* __restrict__ v_w2, const float* __restrict__ v_b2,
    float* __restrict__ out)
{
  __shared__ float s_p[4*6];
  const int t = threadIdx.x, s = blockIdx.x;
  const float hq = fmaxf(Ch[(size_t)s*512 + t]       + q_b1[t], 0.f);
  const float hv = fmaxf(Ch[(size_t)s*512 + 256 + t] + v_b1[t], 0.f);
  float p[6];
  #pragma unroll
  for (int o=0;o<5;o++) p[o] = hq * q_w2[t*5+o];
  p[5] = hv * v_w2[t];
  #pragma unroll
  for (int d_=32; d_; d_>>=1){
    #pragma unroll
    for (int o=0;o<6;o++) p[o] += __shfl_xor(p[o], d_, 64);
  }
  const int w = t>>6, lane = t&63;
  if (lane==0){
    #pragma unroll
    for (int o=0;o<6;o++) s_p[w*6+o] = p[o];
  }
  __syncthreads();
  if (t < 6) s_p[t] = s_p[t] + s_p[6+t] + s_p[12+t] + s_p[18+t];
  __syncthreads();
  if (t < 5){
    const float q0 = s_p[0]+q_b2[0], q1 = s_p[1]+q_b2[1], q2 = s_p[2]+q_b2[2],
                q3 = s_p[3]+q_b2[3], q4 = s_p[4]+q_b2[4];
    const float mean = (q0+q1+q2+q3+q4) / 5.0f;
    const float v = s_p[5] + v_b2[0];
    const float qt = (t==0?q0:t==1?q1:t==2?q2:t==3?q3:q4);
    out[s*5+t] = qt - mean + v;
  }
}

extern "C" void kernel_launch(void* const* d_in, const int* in_sizes, int n_in,
                              void* d_out, int out_size, void* d_ws, size_t ws_size,
                              hipStream_t stream) {
  (void)n_in; (void)out_size; (void)ws_size;
  const float* obs    = (const float*)d_in[0];
  const float* enc_w1 = (const float*)d_in[1];
  const float* enc_b1 = (const float*)d_in[2];
  const float* enc_w2 = (const float*)d_in[3];
  const float* enc_b2 = (const float*)d_in[4];
  const float* wl1    = (const float*)d_in[5];
  const float* wr1    = (const float*)d_in[6];
  const float* att1   = (const float*)d_in[7];
  const float* bias1  = (const float*)d_in[8];
  const float* wl2    = (const float*)d_in[9];
  const float* wr2    = (const float*)d_in[10];
  const float* att2   = (const float*)d_in[11];
  const float* bias2  = (const float*)d_in[12];
  const float* q_w1   = (const float*)d_in[13];
  const float* q_b1   = (const float*)d_in[14];
  const float* q_w2   = (const float*)d_in[15];
  const float* q_b2   = (const float*)d_in[16];
  const float* v_w1   = (const float*)d_in[17];
  const float* v_b1   = (const float*)d_in[18];
  const float* v_w2   = (const float*)d_in[19];
  const float* v_b2   = (const float*)d_in[20];

  char* ws = (char*)d_ws;
  uint_t*   x_pk    = (uint_t*)  (ws + 0);
  uint_t*   xcat_pk = (uint_t*)  (ws + 2097152);
  unsigned* adjw    = (unsigned*)(ws + 2686976);
  int*      aiw     = (int*)     (ws + 2703360);
  uint_t*   x2_pk   = (uint_t*)  (ws + 2703872);
  ushort_t* wl1Thi  = (ushort_t*)(ws + 11092480);
  ushort_t* wl1Tlo  = (ushort_t*)(ws + 11223552);
  ushort_t* wr1Thi  = (ushort_t*)(ws + 11354624);
  ushort_t* wr1Tlo  = (ushort_t*)(ws + 11485696);
  ushort_t* wl2Thi  = (ushort_t*)(ws + 11616768);
  ushort_t* wl2Tlo  = (ushort_t*)(ws + 12141056);
  ushort_t* qw1Thi  = (ushort_t*)(ws + 12665344);
  ushort_t* qw1Tlo  = (ushort_t*)(ws + 13255168);
  ushort_t* vw1Thi  = (ushort_t*)(ws + 13844992);
  ushort_t* vw1Tlo  = (ushort_t*)(ws + 14434816);
  float*    headsC  = (float*)   (ws + 15024640);

  const int bs = in_sizes[0] / 577;   // 128

  prep_kernel<<<512 + 960, 256, 0, stream>>>(obs, enc_w1, enc_b1, enc_w2, enc_b2,
      wl1, wr1, wl2, q_w1, v_w1,
      wl1Thi, wl1Tlo, wr1Thi, wr1Tlo, wl2Thi, wl2Tlo,
      qw1Thi, qw1Tlo, vw1Thi, vw1Tlo,
      x_pk, xcat_pk, adjw, aiw);

  pa1_kernel<<<bs*4, 512, 0, stream>>>(x_pk, wl1Thi, wl1Tlo, wr1Thi, wr1Tlo,
                                       att1, bias1, adjw, aiw, x2_pk, xcat_pk);

  pa2_kernel<<<bs*4, 512, 0, stream>>>(x2_pk, wl2Thi, wl2Tlo, wr2,
                                       att2, bias2, adjw, aiw, xcat_pk);

  mfma_gemm<1152><<<16, 256, 0, stream>>>(xcat_pk, 18432,
      qw1Thi, qw1Tlo, vw1Thi, vw1Tlo, headsC, headsC + 256, 8, 4);

  heads2_kernel<<<bs, 256, 0, stream>>>(headsC, q_b1, q_w2, q_b2, v_b1, v_w2, v_b2,
                                        (float*)d_out);
}